// Round 15
// baseline (136.080 us; speedup 1.0000x reference)
//
#include <hip/hip_runtime.h>
#include <hip/hip_bf16.h>
#include <hip/hip_fp16.h>

#define BB 4
#define CC_ 384
#define HH 32
#define WW 32
#define HWSZ 1024
#define NHD 12
#define HCH 32
#define GG 6
#define NGC_ 64
#define GHD 2
#define HK_ 16
#define WK_ 16
#define NS_ 256
#define RPEW 63
#define SCALE_ 0.17677669529663687f

typedef _Float16 half2_t __attribute__((ext_vector_type(2)));
typedef _Float16 half8_t __attribute__((ext_vector_type(8)));
typedef float f32x4_t __attribute__((ext_vector_type(4)));

#if defined(__has_builtin)
#if __has_builtin(__builtin_amdgcn_fdot2)
#define HAS_FDOT2 1
#endif
#endif

// ---------------- cvt: fp32 -> fp16 flat ----------------
__global__ void cvt_f2h(const float* __restrict__ src, __half* __restrict__ dst, int n4)
{
    int i = blockIdx.x * 256 + threadIdx.x;
    if (i < n4) {
        float4 v = *(const float4*)(src + (size_t)i * 4);
        __half2* d = (__half2*)(dst + (size_t)i * 4);
        d[0] = __floats2half2_rn(v.x, v.y);
        d[1] = __floats2half2_rn(v.z, v.w);
    }
}

// ---------------- cvt_xT: x [b][c][n] fp32 -> xh [b][n][c] fp16 (LDS transpose) ----------------
// grid: (N/64, C/64, B), block 256
__global__ void cvt_xT(const float* __restrict__ X, __half* __restrict__ XT)
{
    __shared__ float tile[64][65];
    const int b = blockIdx.z;
    const int c0 = blockIdx.y * 64, n0 = blockIdx.x * 64;
    const int tid = threadIdx.x;
    const int tn = tid & 63, tg = tid >> 6;
#pragma unroll
    for (int k = 0; k < 16; ++k) {
        int r = k * 4 + tg;
        tile[r][tn] = X[((size_t)(b * CC_ + c0 + r)) * HWSZ + n0 + tn];
    }
    __syncthreads();
    const int cp = tg * 16;
    __half hb[16] __attribute__((aligned(16)));
#pragma unroll
    for (int j = 0; j < 16; ++j) hb[j] = __float2half(tile[cp + j][tn]);
    __half* dst = XT + ((size_t)(b * HWSZ + n0 + tn)) * CC_ + c0 + cp;
    *(uint4*)(dst) = *(uint4*)(hb);
    *(uint4*)(dst + 8) = *(uint4*)(hb + 8);
}

// ---------------- K1/K6: MFMA fp16 conv1x1, fp16 operands (no LDS, no barriers) ----------------
// Wave tile: 16 (o) x 32 (n), 2 mfma_f32_16x16x32_f16 per K-step; block = 4 waves on o.
// grid: (N/32, OC/64, B). A: Wh[o][k] half8; B: XT[n][c] half8 (k-contiguous).
template<int CIN>
__global__ __launch_bounds__(256)
void conv1x1_mfma_h(const __half* __restrict__ Wh, const float* __restrict__ bias,
                    const __half* __restrict__ XT, float* __restrict__ Y, int N, int OC)
{
    const int tid = threadIdx.x;
    const int wv = tid >> 6;
    const int lane = tid & 63;
    const int l15 = lane & 15, lhi = lane >> 4;
    const int otile = blockIdx.y * 64 + wv * 16;
    const int ntile = blockIdx.x * 32;
    const int b = blockIdx.z;

    const __half* Wp = Wh + (size_t)(otile + l15) * CIN + lhi * 8;
    const __half* Xp0 = XT + ((size_t)(b * N + ntile + l15)) * CIN + lhi * 8;
    const __half* Xp1 = Xp0 + (size_t)16 * CIN;

    f32x4_t acc0 = {0.f, 0.f, 0.f, 0.f}, acc1 = {0.f, 0.f, 0.f, 0.f};

#pragma unroll
    for (int k0 = 0; k0 < CIN; k0 += 32) {
        half8_t af = *(const half8_t*)(Wp + k0);
        half8_t b0 = *(const half8_t*)(Xp0 + k0);
        half8_t b1 = *(const half8_t*)(Xp1 + k0);
        acc0 = __builtin_amdgcn_mfma_f32_16x16x32_f16(af, b0, acc0, 0, 0, 0);
        acc1 = __builtin_amdgcn_mfma_f32_16x16x32_f16(af, b1, acc1, 0, 0, 0);
    }
#pragma unroll
    for (int r = 0; r < 4; ++r) {
        float bv = bias[otile + lhi * 4 + r];
        float* yr = Y + ((size_t)(b * OC + otile + lhi * 4 + r)) * N + ntile + l15;
        yr[0]  = acc0[r] + bv;
        yr[16] = acc1[r] + bv;
    }
}

// ---------------- K4: fused K+V 1x1 conv; K -> fp16 [bh][n][32], V -> fp32 [bh][n][32] ----------------
template<int CIN>
__global__ void convkv_kernel(const float* __restrict__ Wk, const float* __restrict__ bk,
                              const float* __restrict__ Wv, const float* __restrict__ bv,
                              const float* __restrict__ X, __half* __restrict__ Yk,
                              float* __restrict__ Yv, int N)
{
    const int otile = blockIdx.x * 4;          // 4-aligned => same head
    const int b = blockIdx.y;
    const int n = threadIdx.x;
    const float* Xb = X + (size_t)b * CIN * N + n;
    const float* Wkr = Wk + (size_t)otile * CIN;
    const float* Wvr = Wv + (size_t)otile * CIN;

    float ak0 = 0.f, ak1 = 0.f, ak2 = 0.f, ak3 = 0.f;
    float av0 = 0.f, av1 = 0.f, av2 = 0.f, av3 = 0.f;
#pragma unroll 4
    for (int c = 0; c < CIN; ++c) {
        float xv = Xb[(size_t)c * N];
        ak0 = fmaf(Wkr[c], xv, ak0);
        ak1 = fmaf(Wkr[CIN + c], xv, ak1);
        ak2 = fmaf(Wkr[2 * CIN + c], xv, ak2);
        ak3 = fmaf(Wkr[3 * CIN + c], xv, ak3);
        av0 = fmaf(Wvr[c], xv, av0);
        av1 = fmaf(Wvr[CIN + c], xv, av1);
        av2 = fmaf(Wvr[2 * CIN + c], xv, av2);
        av3 = fmaf(Wvr[3 * CIN + c], xv, av3);
    }
    const int h = otile >> 5, cc = otile & 31;
    const size_t obase = (((size_t)(b * NHD + h) * N) + n) * 32 + cc;
    __half2* yk2 = (__half2*)(Yk + obase);
    yk2[0] = __floats2half2_rn(ak0 + bk[otile + 0], ak1 + bk[otile + 1]);
    yk2[1] = __floats2half2_rn(ak2 + bk[otile + 2], ak3 + bk[otile + 3]);
    *(float4*)(Yv + obase) = make_float4(av0 + bv[otile + 0], av1 + bv[otile + 1],
                                         av2 + bv[otile + 2], av3 + bv[otile + 3]);
}

// ---------------- K2a: depthwise conv 5x5 stride 2, transposed output [bg][pos][ch] ----------------
__global__ void offset_dw_kernel(const float* __restrict__ qb, const float* __restrict__ dww,
                                 const float* __restrict__ dwb, float* __restrict__ cobuf)
{
    __shared__ float img[HWSZ];
    const int c = blockIdx.x, bg = blockIdx.y;
    const int b = bg / GG, g = bg - b * GG;
    const int tid = threadIdx.x;
    const float* src = qb + ((size_t)(b * CC_ + g * NGC_ + c)) * HWSZ;
#pragma unroll
    for (int e = tid; e < HWSZ; e += 256) img[e] = src[e];
    __syncthreads();
    const int oy = tid >> 4, ox = tid & 15;
    float s = dwb[c];
    const float* wf = dww + c * 25;
    const int iy0 = oy * 2 - 2, ix0 = ox * 2 - 2;
#pragma unroll
    for (int ky = 0; ky < 5; ++ky) {
        int iy = iy0 + ky;
        if (iy < 0 || iy > 31) continue;
#pragma unroll
        for (int kx = 0; kx < 5; ++kx) {
            int ix = ix0 + kx;
            if (ix < 0 || ix > 31) continue;
            s = fmaf(img[iy * 32 + ix], wf[ky * 5 + kx], s);
        }
    }
    cobuf[((size_t)(bg * 256 + tid)) * NGC_ + c] = s;   // [bg][pos][ch]
}

// ---------------- K2b: LN + GELU + pw + tanh, one wave per position ----------------
__global__ void offset_fin_kernel(const float* __restrict__ cobuf, const float* __restrict__ lng,
                                  const float* __restrict__ lnb, const float* __restrict__ pww,
                                  float* __restrict__ posb)
{
    const int lane = threadIdx.x & 63;
    const int gpos = blockIdx.x * 4 + (threadIdx.x >> 6);   // 0..6143
    const int bg = gpos >> 8, pos = gpos & 255;
    const int oy = (pos >> 4), ox = pos & 15;

    float v = cobuf[(size_t)gpos * NGC_ + lane];
    float s1 = v, s2 = v * v;
#pragma unroll
    for (int off = 32; off >= 1; off >>= 1) {
        s1 += __shfl_xor(s1, off);
        s2 += __shfl_xor(s2, off);
    }
    float mu = s1 * (1.f / 64.f);
    float var = s2 * (1.f / 64.f) - mu * mu;
    float rstd = rsqrtf(var + 1e-5f);
    float t = (v - mu) * rstd * lng[lane] + lnb[lane];
    float gv = 0.5f * t * (1.f + erff(t * 0.70710678118654752f));
    float o0 = pww[lane] * gv;
    float o1 = pww[64 + lane] * gv;
#pragma unroll
    for (int off = 32; off >= 1; off >>= 1) {
        o0 += __shfl_xor(o0, off);
        o1 += __shfl_xor(o1, off);
    }
    if (lane == 0) {
        float py = tanhf(o0) * (2.f / 15.f) + ((0.5f + (float)oy) * (1.f / 15.f)) * 2.f - 1.f;
        float px = tanhf(o1) * (2.f / 15.f) + ((0.5f + (float)ox) * (1.f / 15.f)) * 2.f - 1.f;
        posb[bg * 512 + pos * 2 + 0] = py;
        posb[bg * 512 + pos * 2 + 1] = px;
    }
}

// ---------------- K3: bilinear KV sampling ----------------
__global__ void sample_xs_kernel(const float* __restrict__ x, const float* __restrict__ posb,
                                 float* __restrict__ xsb)
{
    const int cc = blockIdx.x, bg = blockIdx.y;
    const int b = bg / GG, g = bg - b * GG;
    const int s = threadIdx.x;
    float py = posb[bg * 512 + s * 2 + 0];
    float px = posb[bg * 512 + s * 2 + 1];
    float xi = (px + 1.f) * 0.5f * 31.f;
    float yi = (py + 1.f) * 0.5f * 31.f;
    float x0f = floorf(xi), y0f = floorf(yi);
    int x0 = (int)x0f, y0 = (int)y0f;
    float wx1 = xi - x0f, wy1 = yi - y0f;
    const float* img = x + ((size_t)(b * CC_ + g * NGC_ + cc)) * HWSZ;
    float acc = 0.f;
#pragma unroll
    for (int t = 0; t < 4; ++t) {
        int iy = y0 + (t >> 1), ix = x0 + (t & 1);
        float w = ((t >> 1) ? wy1 : 1.f - wy1) * ((t & 1) ? wx1 : 1.f - wx1);
        if (iy >= 0 && iy <= 31 && ix >= 0 && ix <= 31)
            acc = fmaf(img[iy * 32 + ix], w, acc);
    }
    xsb[((size_t)(b * CC_ + g * NGC_ + cc)) * NS_ + s] = acc;
}

// ---------------- K5: fused attention, fp16 K via v_dot2, scalar K/V loads ----------------
// grid: (16 qtiles, 48 bh), block 512 = 64 queries(lanes) x 8 sample-groups(waves).
// Output: aoT [b][n][c] fp16 (feeds conv_out MFMA directly).
__launch_bounds__(512)
__global__ void attn_kernel(const float* __restrict__ qb, const __half* __restrict__ kt,
                            const float* __restrict__ vt, const float* __restrict__ posb,
                            const float* __restrict__ rpe, __half* __restrict__ aoT)
{
    // union: phase 1 = rph (fp16 rpe, 8KB) + ps (2KB); phase 2 = lbuf[512] + red[512]f4
    __shared__ float smem[2560];
    __half* rph = (__half*)smem;          // 4096 halfs (3969 used)
    float* ps = smem + 2048;              // 512 floats
    const int bh = blockIdx.y;
    const int b = bh / NHD, h = bh - b * NHD;
    const int bg = b * GG + (h >> 1);
    const int tid = threadIdx.x;

    for (int e = tid; e < RPEW * RPEW; e += 512)
        rph[e] = __float2half(rpe[(size_t)h * (RPEW * RPEW) + e]);
    ps[tid] = posb[bg * 512 + tid];
    __syncthreads();

    const int q = tid & 63;
    const int sgrp = __builtin_amdgcn_readfirstlane(tid >> 6);  // wave-uniform -> scalar K/V loads
    const int qidx = blockIdx.x * 64 + q;
    const int row = qidx >> 5, col = qidx & 31;
    const float gyq = (float)row * (2.f / 31.f) - 1.f;
    const float gxq = (float)col * (2.f / 31.f) - 1.f;

    // Q fragment: fp16 pairs with SCALE pre-folded (for v_dot2)
    half2_t qh[16];
    const float* qg = qb + ((size_t)(b * CC_ + h * HCH)) * HWSZ + qidx;
#pragma unroll
    for (int i = 0; i < 16; ++i) {
        float q0 = qg[(size_t)(2 * i) * HWSZ] * SCALE_;
        float q1 = qg[(size_t)(2 * i + 1) * HWSZ] * SCALE_;
        half2_t hh; hh[0] = (_Float16)q0; hh[1] = (_Float16)q1;
        qh[i] = hh;
    }

    float l = 0.f;
    float oacc[32];
#pragma unroll
    for (int c = 0; c < 32; ++c) oacc[c] = 0.f;

    const unsigned* kb2 = (const unsigned*)kt + ((size_t)bh * NS_) * 16;
    const float* vb2 = vt + ((size_t)bh * NS_) * 32;

    const int s0 = sgrp * 32;
#pragma unroll 2
    for (int s = s0; s < s0 + 32; ++s) {
        const unsigned* kr = kb2 + s * 16;   // wave-uniform -> s_load (64B)
        float d0 = 0.f, d1 = 0.f, d2 = 0.f, d3 = 0.f;
#pragma unroll
        for (int i4 = 0; i4 < 4; ++i4) {
            unsigned ku0 = kr[i4 * 4 + 0], ku1 = kr[i4 * 4 + 1];
            unsigned ku2 = kr[i4 * 4 + 2], ku3 = kr[i4 * 4 + 3];
#ifdef HAS_FDOT2
            d0 = __builtin_amdgcn_fdot2(qh[i4 * 4 + 0], __builtin_bit_cast(half2_t, ku0), d0, false);
            d1 = __builtin_amdgcn_fdot2(qh[i4 * 4 + 1], __builtin_bit_cast(half2_t, ku1), d1, false);
            d2 = __builtin_amdgcn_fdot2(qh[i4 * 4 + 2], __builtin_bit_cast(half2_t, ku2), d2, false);
            d3 = __builtin_amdgcn_fdot2(qh[i4 * 4 + 3], __builtin_bit_cast(half2_t, ku3), d3, false);
#else
            {
                half2_t k0 = __builtin_bit_cast(half2_t, ku0), k1 = __builtin_bit_cast(half2_t, ku1);
                half2_t k2 = __builtin_bit_cast(half2_t, ku2), k3 = __builtin_bit_cast(half2_t, ku3);
                half2_t a0 = qh[i4 * 4 + 0], a1 = qh[i4 * 4 + 1];
                half2_t a2 = qh[i4 * 4 + 2], a3 = qh[i4 * 4 + 3];
                d0 = fmaf((float)a0[0], (float)k0[0], d0); d0 = fmaf((float)a0[1], (float)k0[1], d0);
                d1 = fmaf((float)a1[0], (float)k1[0], d1); d1 = fmaf((float)a1[1], (float)k1[1], d1);
                d2 = fmaf((float)a2[0], (float)k2[0], d2); d2 = fmaf((float)a2[1], (float)k2[1], d2);
                d3 = fmaf((float)a3[0], (float)k3[0], d3); d3 = fmaf((float)a3[1], (float)k3[1], d3);
            }
#endif
        }
        float dot = (d0 + d1) + (d2 + d3);   // already scaled

        float2 pp = *(const float2*)(ps + (s << 1));   // (py, px)
        float dy = (gyq - pp.x) * 0.5f, dx = (gxq - pp.y) * 0.5f;
        float yi = (dy + 1.f) * 31.f,  xi = (dx + 1.f) * 31.f;
        float y0f = floorf(yi), x0f = floorf(xi);
        int iy = (int)y0f, ix = (int)x0f;
        float wy1 = yi - y0f, wx1 = xi - x0f;
        float wy0 = 1.f - wy1, wx0 = 1.f - wx1;
        if ((unsigned)iy > 62u)       wy0 = 0.f;
        if ((unsigned)(iy + 1) > 62u) wy1 = 0.f;
        if ((unsigned)ix > 62u)       wx0 = 0.f;
        if ((unsigned)(ix + 1) > 62u) wx1 = 0.f;
        int ry0 = min(max(iy, 0), 62) * 63;
        int ry1 = min(max(iy + 1, 0), 62) * 63;
        int cx0 = min(max(ix, 0), 62);
        int cx1 = min(max(ix + 1, 0), 62);
        float t00 = __half2float(rph[ry0 + cx0]), t01 = __half2float(rph[ry0 + cx1]);
        float t10 = __half2float(rph[ry1 + cx0]), t11 = __half2float(rph[ry1 + cx1]);
        float bias = wy0 * fmaf(wx0, t00, wx1 * t01)
                   + wy1 * fmaf(wx0, t10, wx1 * t11);

        // logits structurally small: exp without max tracking
        float p = __expf(dot + bias);
        l += p;

        const float* vr = vb2 + s * 32;   // wave-uniform -> s_load
#pragma unroll
        for (int c8 = 0; c8 < 4; ++c8) {
            const int o = c8 * 8;
            float v0 = vr[o + 0], v1 = vr[o + 1], v2 = vr[o + 2], v3 = vr[o + 3];
            float v4 = vr[o + 4], v5 = vr[o + 5], v6 = vr[o + 6], v7 = vr[o + 7];
            oacc[o + 0] = fmaf(p, v0, oacc[o + 0]); oacc[o + 1] = fmaf(p, v1, oacc[o + 1]);
            oacc[o + 2] = fmaf(p, v2, oacc[o + 2]); oacc[o + 3] = fmaf(p, v3, oacc[o + 3]);
            oacc[o + 4] = fmaf(p, v4, oacc[o + 4]); oacc[o + 5] = fmaf(p, v5, oacc[o + 5]);
            oacc[o + 6] = fmaf(p, v6, oacc[o + 6]); oacc[o + 7] = fmaf(p, v7, oacc[o + 7]);
        }
    }

    // ---- merge 8 sample-group waves: plain sums (rph/ps dead now) ----
    __syncthreads();
    float* lbuf = smem;                    // 512 floats
    float4* red = (float4*)(smem + 512);   // 512 float4
    lbuf[tid] = l;
    __syncthreads();
    float L = 0.f;
#pragma unroll
    for (int j = 0; j < 8; ++j) L += lbuf[q + 64 * j];
    float scale = 1.f / L;

    __half* ogh = aoT + ((size_t)(b * HWSZ + qidx)) * CC_ + h * HCH;
#pragma unroll
    for (int cb = 0; cb < 8; ++cb) {
        __syncthreads();
        red[tid] = make_float4(oacc[cb * 4 + 0] * scale, oacc[cb * 4 + 1] * scale,
                               oacc[cb * 4 + 2] * scale, oacc[cb * 4 + 3] * scale);
        __syncthreads();
        if (sgrp == 0) {
            float4 sm = red[q];
#pragma unroll
            for (int j = 1; j < 8; ++j) {
                float4 a = red[q + 64 * j];
                sm.x += a.x; sm.y += a.y; sm.z += a.z; sm.w += a.w;
            }
            __half2* d = (__half2*)(ogh + cb * 4);
            d[0] = __floats2half2_rn(sm.x, sm.y);
            d[1] = __floats2half2_rn(sm.z, sm.w);
        }
    }
}

extern "C" void kernel_launch(void* const* d_in, const int* in_sizes, int n_in,
                              void* d_out, int out_size, void* d_ws, size_t ws_size,
                              hipStream_t stream) {
    (void)in_sizes; (void)n_in; (void)out_size; (void)ws_size;
    const float* x   = (const float*)d_in[0];
    const float* Wq  = (const float*)d_in[1];
    const float* bq  = (const float*)d_in[2];
    const float* Wk  = (const float*)d_in[3];
    const float* bk  = (const float*)d_in[4];
    const float* Wv  = (const float*)d_in[5];
    const float* bv  = (const float*)d_in[6];
    const float* Wo  = (const float*)d_in[7];
    const float* bo  = (const float*)d_in[8];
    const float* dww = (const float*)d_in[9];
    const float* dwb = (const float*)d_in[10];
    const float* lng = (const float*)d_in[11];
    const float* lnb = (const float*)d_in[12];
    const float* pww = (const float*)d_in[13];
    const float* rpe = (const float*)d_in[14];
    float* out = (float*)d_out;

    // Workspace layout (float slots). xh/aoT are B*HWSZ*CC_ halfs = 786432 float
    // slots EACH (R12-R14 bug: sized 196608 -> cvt_xT/attn overwrote wqh/woh).
    // xh is dead after conv_q; attn fully overwrites the region as aoT -> alias.
    float* p = (float*)d_ws;
    float* qbuf  = p; p += 1572864;                 // fp32 [b][c][n]
    float* posb  = p; p += 12288;
    float* xsb   = p; p += 393216;
    __half* ktb  = (__half*)p; p += 196608;         // 393216 halfs: K fp16 [bh][s][32]
    float* vtb   = p; p += 393216;                  // V fp32 [bh][s][32]
    float* cobuf = p; p += 393216;
    __half* xh   = (__half*)p;                      // 1572864 halfs: [b][n][c]
    __half* aoT  = (__half*)p; p += 786432;         // aliases xh (xh dead after conv_q)
    __half* wqh  = (__half*)p; p += 73728;          // 147456 halfs (CC_*CC_)
    __half* woh  = (__half*)p; p += 73728;          // 147456 halfs
    // total: 3,895,296 floats = 15.58 MB (< 16.6 MB validated in R1-R8)

    cvt_f2h<<<dim3((CC_ * CC_ / 4 + 255) / 256), 256, 0, stream>>>(Wq, wqh, CC_ * CC_ / 4);
    cvt_f2h<<<dim3((CC_ * CC_ / 4 + 255) / 256), 256, 0, stream>>>(Wo, woh, CC_ * CC_ / 4);
    cvt_xT<<<dim3(HWSZ / 64, CC_ / 64, BB), 256, 0, stream>>>(x, xh);
    conv1x1_mfma_h<CC_><<<dim3(HWSZ / 32, CC_ / 64, BB), 256, 0, stream>>>(wqh, bq, xh, qbuf, HWSZ, CC_);
    offset_dw_kernel<<<dim3(NGC_, 24), 256, 0, stream>>>(qbuf, dww, dwb, cobuf);
    offset_fin_kernel<<<dim3(1536), 256, 0, stream>>>(cobuf, lng, lnb, pww, posb);
    sample_xs_kernel<<<dim3(NGC_, 24), 256, 0, stream>>>(x, posb, xsb);
    convkv_kernel<CC_><<<dim3(CC_ / 4, BB), 256, 0, stream>>>(Wk, bk, Wv, bv, xsb, ktb, vtb, NS_);
    attn_kernel<<<dim3(16, BB * NHD), 512, 0, stream>>>(qbuf, ktb, vtb, posb, rpe, aoT);
    conv1x1_mfma_h<CC_><<<dim3(HWSZ / 32, CC_ / 64, BB), 256, 0, stream>>>(woh, bo, aoT, out, HWSZ, CC_);
}

// Round 16
// 112.672 us; speedup vs baseline: 1.2078x; 1.2078x over previous
//
#include <hip/hip_runtime.h>
#include <hip/hip_bf16.h>
#include <hip/hip_fp16.h>

#define BB 4
#define CC_ 384
#define HH 32
#define WW 32
#define HWSZ 1024
#define NHD 12
#define HCH 32
#define GG 6
#define NGC_ 64
#define GHD 2
#define HK_ 16
#define WK_ 16
#define NS_ 256
#define RPEW 63
#define SCALE_ 0.17677669529663687f

typedef _Float16 half2_t __attribute__((ext_vector_type(2)));
typedef _Float16 half8_t __attribute__((ext_vector_type(8)));
typedef float f32x4_t __attribute__((ext_vector_type(4)));

#if defined(__has_builtin)
#if __has_builtin(__builtin_amdgcn_fdot2)
#define HAS_FDOT2 1
#endif
#endif

// ---------------- cvt: fp32 -> fp16 flat ----------------
__global__ void cvt_f2h(const float* __restrict__ src, __half* __restrict__ dst, int n4)
{
    int i = blockIdx.x * 256 + threadIdx.x;
    if (i < n4) {
        float4 v = *(const float4*)(src + (size_t)i * 4);
        __half2* d = (__half2*)(dst + (size_t)i * 4);
        d[0] = __floats2half2_rn(v.x, v.y);
        d[1] = __floats2half2_rn(v.z, v.w);
    }
}

// ---------------- cvt_T_f2h: X [b][c][n] fp32 -> XT [b][n][c] fp16 (LDS transpose) ----------------
// grid: (N/64, C/64, B), block 256
__global__ void cvt_T_f2h(const float* __restrict__ X, __half* __restrict__ XT, int C, int N)
{
    __shared__ float tile[64][65];
    const int b = blockIdx.z;
    const int c0 = blockIdx.y * 64, n0 = blockIdx.x * 64;
    const int tid = threadIdx.x;
    const int tn = tid & 63, tg = tid >> 6;
#pragma unroll
    for (int k = 0; k < 16; ++k) {
        int r = k * 4 + tg;
        tile[r][tn] = X[((size_t)(b * C + c0 + r)) * N + n0 + tn];
    }
    __syncthreads();
    const int cp = tg * 16;
    __half hb[16] __attribute__((aligned(16)));
#pragma unroll
    for (int j = 0; j < 16; ++j) hb[j] = __float2half(tile[cp + j][tn]);
    __half* dst = XT + ((size_t)(b * N + n0 + tn)) * C + c0 + cp;
    *(uint4*)(dst) = *(uint4*)(hb);
    *(uint4*)(dst + 8) = *(uint4*)(hb + 8);
}

// ---------------- K1/K6: MFMA fp16 conv1x1, fp16 operands (no LDS, no barriers) ----------------
// Wave tile: 16 (o) x 32 (n), 2 mfma_f32_16x16x32_f16 per K-step; block = 4 waves on o.
// grid: (N/32, OC/64, B). A: Wh[o][k] half8; B: XT[n][c] half8 (k-contiguous).
template<int CIN>
__global__ __launch_bounds__(256)
void conv1x1_mfma_h(const __half* __restrict__ Wh, const float* __restrict__ bias,
                    const __half* __restrict__ XT, float* __restrict__ Y, int N, int OC)
{
    const int tid = threadIdx.x;
    const int wv = tid >> 6;
    const int lane = tid & 63;
    const int l15 = lane & 15, lhi = lane >> 4;
    const int otile = blockIdx.y * 64 + wv * 16;
    const int ntile = blockIdx.x * 32;
    const int b = blockIdx.z;

    const __half* Wp = Wh + (size_t)(otile + l15) * CIN + lhi * 8;
    const __half* Xp0 = XT + ((size_t)(b * N + ntile + l15)) * CIN + lhi * 8;
    const __half* Xp1 = Xp0 + (size_t)16 * CIN;

    f32x4_t acc0 = {0.f, 0.f, 0.f, 0.f}, acc1 = {0.f, 0.f, 0.f, 0.f};

#pragma unroll
    for (int k0 = 0; k0 < CIN; k0 += 32) {
        half8_t af = *(const half8_t*)(Wp + k0);
        half8_t b0 = *(const half8_t*)(Xp0 + k0);
        half8_t b1 = *(const half8_t*)(Xp1 + k0);
        acc0 = __builtin_amdgcn_mfma_f32_16x16x32_f16(af, b0, acc0, 0, 0, 0);
        acc1 = __builtin_amdgcn_mfma_f32_16x16x32_f16(af, b1, acc1, 0, 0, 0);
    }
#pragma unroll
    for (int r = 0; r < 4; ++r) {
        float bv = bias[otile + lhi * 4 + r];
        float* yr = Y + ((size_t)(b * OC + otile + lhi * 4 + r)) * N + ntile + l15;
        yr[0]  = acc0[r] + bv;
        yr[16] = acc1[r] + bv;
    }
}

// ---------------- K4: MFMA fused K+V conv; K -> fp16 [bh][s][32], V -> fp32 [bh][s][32] ----------------
// Wave tile: 16 (o) x 32 (s); per K-step 4 loads + 4 MFMA. grid: (NS/32, CC/64, B), block 256.
template<int CIN>
__global__ __launch_bounds__(256)
void convkv_mfma(const __half* __restrict__ Wkh, const float* __restrict__ bk,
                 const __half* __restrict__ Wvh, const float* __restrict__ bv,
                 const __half* __restrict__ XS, __half* __restrict__ Yk,
                 float* __restrict__ Yv)
{
    const int tid = threadIdx.x;
    const int wv = tid >> 6;
    const int lane = tid & 63;
    const int l15 = lane & 15, lhi = lane >> 4;
    const int otile = blockIdx.y * 64 + wv * 16;
    const int stile = blockIdx.x * 32;
    const int b = blockIdx.z;

    const __half* Wkp = Wkh + (size_t)(otile + l15) * CIN + lhi * 8;
    const __half* Wvp = Wvh + (size_t)(otile + l15) * CIN + lhi * 8;
    const __half* Xp0 = XS + ((size_t)(b * NS_ + stile + l15)) * CIN + lhi * 8;
    const __half* Xp1 = Xp0 + (size_t)16 * CIN;

    f32x4_t ka0 = {0.f,0.f,0.f,0.f}, ka1 = {0.f,0.f,0.f,0.f};
    f32x4_t va0 = {0.f,0.f,0.f,0.f}, va1 = {0.f,0.f,0.f,0.f};

#pragma unroll
    for (int c0 = 0; c0 < CIN; c0 += 32) {
        half8_t ak = *(const half8_t*)(Wkp + c0);
        half8_t av = *(const half8_t*)(Wvp + c0);
        half8_t b0 = *(const half8_t*)(Xp0 + c0);
        half8_t b1 = *(const half8_t*)(Xp1 + c0);
        ka0 = __builtin_amdgcn_mfma_f32_16x16x32_f16(ak, b0, ka0, 0, 0, 0);
        ka1 = __builtin_amdgcn_mfma_f32_16x16x32_f16(ak, b1, ka1, 0, 0, 0);
        va0 = __builtin_amdgcn_mfma_f32_16x16x32_f16(av, b0, va0, 0, 0, 0);
        va1 = __builtin_amdgcn_mfma_f32_16x16x32_f16(av, b1, va1, 0, 0, 0);
    }
    const int h = otile >> 5;
    const int c32 = (otile & 31) + lhi * 4;
    const size_t bh = (size_t)(b * NHD + h);
    float bk0 = bk[otile + lhi * 4 + 0], bk1 = bk[otile + lhi * 4 + 1];
    float bk2 = bk[otile + lhi * 4 + 2], bk3 = bk[otile + lhi * 4 + 3];
    float bv0 = bv[otile + lhi * 4 + 0], bv1 = bv[otile + lhi * 4 + 1];
    float bv2 = bv[otile + lhi * 4 + 2], bv3 = bv[otile + lhi * 4 + 3];

    // subtile 0: s = stile + l15
    {
        size_t base = (bh * NS_ + stile + l15) * 32 + c32;
        __half2 kh[2];
        kh[0] = __floats2half2_rn(ka0[0] + bk0, ka0[1] + bk1);
        kh[1] = __floats2half2_rn(ka0[2] + bk2, ka0[3] + bk3);
        *(uint2*)(Yk + base) = *(uint2*)kh;
        *(float4*)(Yv + base) = make_float4(va0[0] + bv0, va0[1] + bv1, va0[2] + bv2, va0[3] + bv3);
    }
    // subtile 1: s = stile + 16 + l15
    {
        size_t base = (bh * NS_ + stile + 16 + l15) * 32 + c32;
        __half2 kh[2];
        kh[0] = __floats2half2_rn(ka1[0] + bk0, ka1[1] + bk1);
        kh[1] = __floats2half2_rn(ka1[2] + bk2, ka1[3] + bk3);
        *(uint2*)(Yk + base) = *(uint2*)kh;
        *(float4*)(Yv + base) = make_float4(va1[0] + bv0, va1[1] + bv1, va1[2] + bv2, va1[3] + bv3);
    }
}

// ---------------- K2a: depthwise conv 5x5 stride 2, transposed output [bg][pos][ch] ----------------
__global__ void offset_dw_kernel(const float* __restrict__ qb, const float* __restrict__ dww,
                                 const float* __restrict__ dwb, float* __restrict__ cobuf)
{
    __shared__ float img[HWSZ];
    const int c = blockIdx.x, bg = blockIdx.y;
    const int b = bg / GG, g = bg - b * GG;
    const int tid = threadIdx.x;
    const float* src = qb + ((size_t)(b * CC_ + g * NGC_ + c)) * HWSZ;
#pragma unroll
    for (int e = tid; e < HWSZ; e += 256) img[e] = src[e];
    __syncthreads();
    const int oy = tid >> 4, ox = tid & 15;
    float s = dwb[c];
    const float* wf = dww + c * 25;
    const int iy0 = oy * 2 - 2, ix0 = ox * 2 - 2;
#pragma unroll
    for (int ky = 0; ky < 5; ++ky) {
        int iy = iy0 + ky;
        if (iy < 0 || iy > 31) continue;
#pragma unroll
        for (int kx = 0; kx < 5; ++kx) {
            int ix = ix0 + kx;
            if (ix < 0 || ix > 31) continue;
            s = fmaf(img[iy * 32 + ix], wf[ky * 5 + kx], s);
        }
    }
    cobuf[((size_t)(bg * 256 + tid)) * NGC_ + c] = s;   // [bg][pos][ch]
}

// ---------------- K2b: LN + GELU + pw + tanh, one wave per position ----------------
__global__ void offset_fin_kernel(const float* __restrict__ cobuf, const float* __restrict__ lng,
                                  const float* __restrict__ lnb, const float* __restrict__ pww,
                                  float* __restrict__ posb)
{
    const int lane = threadIdx.x & 63;
    const int gpos = blockIdx.x * 4 + (threadIdx.x >> 6);   // 0..6143
    const int bg = gpos >> 8, pos = gpos & 255;
    const int oy = (pos >> 4), ox = pos & 15;

    float v = cobuf[(size_t)gpos * NGC_ + lane];
    float s1 = v, s2 = v * v;
#pragma unroll
    for (int off = 32; off >= 1; off >>= 1) {
        s1 += __shfl_xor(s1, off);
        s2 += __shfl_xor(s2, off);
    }
    float mu = s1 * (1.f / 64.f);
    float var = s2 * (1.f / 64.f) - mu * mu;
    float rstd = rsqrtf(var + 1e-5f);
    float t = (v - mu) * rstd * lng[lane] + lnb[lane];
    float gv = 0.5f * t * (1.f + erff(t * 0.70710678118654752f));
    float o0 = pww[lane] * gv;
    float o1 = pww[64 + lane] * gv;
#pragma unroll
    for (int off = 32; off >= 1; off >>= 1) {
        o0 += __shfl_xor(o0, off);
        o1 += __shfl_xor(o1, off);
    }
    if (lane == 0) {
        float py = tanhf(o0) * (2.f / 15.f) + ((0.5f + (float)oy) * (1.f / 15.f)) * 2.f - 1.f;
        float px = tanhf(o1) * (2.f / 15.f) + ((0.5f + (float)ox) * (1.f / 15.f)) * 2.f - 1.f;
        posb[bg * 512 + pos * 2 + 0] = py;
        posb[bg * 512 + pos * 2 + 1] = px;
    }
}

// ---------------- K3: bilinear KV sampling ----------------
__global__ void sample_xs_kernel(const float* __restrict__ x, const float* __restrict__ posb,
                                 float* __restrict__ xsb)
{
    const int cc = blockIdx.x, bg = blockIdx.y;
    const int b = bg / GG, g = bg - b * GG;
    const int s = threadIdx.x;
    float py = posb[bg * 512 + s * 2 + 0];
    float px = posb[bg * 512 + s * 2 + 1];
    float xi = (px + 1.f) * 0.5f * 31.f;
    float yi = (py + 1.f) * 0.5f * 31.f;
    float x0f = floorf(xi), y0f = floorf(yi);
    int x0 = (int)x0f, y0 = (int)y0f;
    float wx1 = xi - x0f, wy1 = yi - y0f;
    const float* img = x + ((size_t)(b * CC_ + g * NGC_ + cc)) * HWSZ;
    float acc = 0.f;
#pragma unroll
    for (int t = 0; t < 4; ++t) {
        int iy = y0 + (t >> 1), ix = x0 + (t & 1);
        float w = ((t >> 1) ? wy1 : 1.f - wy1) * ((t & 1) ? wx1 : 1.f - wx1);
        if (iy >= 0 && iy <= 31 && ix >= 0 && ix <= 31)
            acc = fmaf(img[iy * 32 + ix], w, acc);
    }
    xsb[((size_t)(b * CC_ + g * NGC_ + cc)) * NS_ + s] = acc;
}

// ---------------- K5: fused attention, fp16 K via v_dot2, scalar K/V loads ----------------
// grid: (16 qtiles, 48 bh), block 512 = 64 queries(lanes) x 8 sample-groups(waves).
// Output: aoT [b][n][c] fp16 (feeds conv_out MFMA directly).
__launch_bounds__(512)
__global__ void attn_kernel(const float* __restrict__ qb, const __half* __restrict__ kt,
                            const float* __restrict__ vt, const float* __restrict__ posb,
                            const float* __restrict__ rpe, __half* __restrict__ aoT)
{
    // union: phase 1 = rph (fp16 rpe, 8KB) + ps (2KB); phase 2 = lbuf[512] + red[512]f4
    __shared__ float smem[2560];
    __half* rph = (__half*)smem;          // 4096 halfs (3969 used)
    float* ps = smem + 2048;              // 512 floats
    const int bh = blockIdx.y;
    const int b = bh / NHD, h = bh - b * NHD;
    const int bg = b * GG + (h >> 1);
    const int tid = threadIdx.x;

    for (int e = tid; e < RPEW * RPEW; e += 512)
        rph[e] = __float2half(rpe[(size_t)h * (RPEW * RPEW) + e]);
    ps[tid] = posb[bg * 512 + tid];
    __syncthreads();

    const int q = tid & 63;
    const int sgrp = __builtin_amdgcn_readfirstlane(tid >> 6);  // wave-uniform -> scalar K/V loads
    const int qidx = blockIdx.x * 64 + q;
    const int row = qidx >> 5, col = qidx & 31;
    const float gyq = (float)row * (2.f / 31.f) - 1.f;
    const float gxq = (float)col * (2.f / 31.f) - 1.f;

    // Q fragment: fp16 pairs with SCALE pre-folded (for v_dot2)
    half2_t qh[16];
    const float* qg = qb + ((size_t)(b * CC_ + h * HCH)) * HWSZ + qidx;
#pragma unroll
    for (int i = 0; i < 16; ++i) {
        float q0 = qg[(size_t)(2 * i) * HWSZ] * SCALE_;
        float q1 = qg[(size_t)(2 * i + 1) * HWSZ] * SCALE_;
        half2_t hh; hh[0] = (_Float16)q0; hh[1] = (_Float16)q1;
        qh[i] = hh;
    }

    float l = 0.f;
    float oacc[32];
#pragma unroll
    for (int c = 0; c < 32; ++c) oacc[c] = 0.f;

    const unsigned* kb2 = (const unsigned*)kt + ((size_t)bh * NS_) * 16;
    const float* vb2 = vt + ((size_t)bh * NS_) * 32;

    const int s0 = sgrp * 32;
#pragma unroll 2
    for (int s = s0; s < s0 + 32; ++s) {
        const unsigned* kr = kb2 + s * 16;   // wave-uniform -> s_load (64B)
        float d0 = 0.f, d1 = 0.f, d2 = 0.f, d3 = 0.f;
#pragma unroll
        for (int i4 = 0; i4 < 4; ++i4) {
            unsigned ku0 = kr[i4 * 4 + 0], ku1 = kr[i4 * 4 + 1];
            unsigned ku2 = kr[i4 * 4 + 2], ku3 = kr[i4 * 4 + 3];
#ifdef HAS_FDOT2
            d0 = __builtin_amdgcn_fdot2(qh[i4 * 4 + 0], __builtin_bit_cast(half2_t, ku0), d0, false);
            d1 = __builtin_amdgcn_fdot2(qh[i4 * 4 + 1], __builtin_bit_cast(half2_t, ku1), d1, false);
            d2 = __builtin_amdgcn_fdot2(qh[i4 * 4 + 2], __builtin_bit_cast(half2_t, ku2), d2, false);
            d3 = __builtin_amdgcn_fdot2(qh[i4 * 4 + 3], __builtin_bit_cast(half2_t, ku3), d3, false);
#else
            {
                half2_t k0 = __builtin_bit_cast(half2_t, ku0), k1 = __builtin_bit_cast(half2_t, ku1);
                half2_t k2 = __builtin_bit_cast(half2_t, ku2), k3 = __builtin_bit_cast(half2_t, ku3);
                half2_t a0 = qh[i4 * 4 + 0], a1 = qh[i4 * 4 + 1];
                half2_t a2 = qh[i4 * 4 + 2], a3 = qh[i4 * 4 + 3];
                d0 = fmaf((float)a0[0], (float)k0[0], d0); d0 = fmaf((float)a0[1], (float)k0[1], d0);
                d1 = fmaf((float)a1[0], (float)k1[0], d1); d1 = fmaf((float)a1[1], (float)k1[1], d1);
                d2 = fmaf((float)a2[0], (float)k2[0], d2); d2 = fmaf((float)a2[1], (float)k2[1], d2);
                d3 = fmaf((float)a3[0], (float)k3[0], d3); d3 = fmaf((float)a3[1], (float)k3[1], d3);
            }
#endif
        }
        float dot = (d0 + d1) + (d2 + d3);   // already scaled

        float2 pp = *(const float2*)(ps + (s << 1));   // (py, px)
        float dy = (gyq - pp.x) * 0.5f, dx = (gxq - pp.y) * 0.5f;
        float yi = (dy + 1.f) * 31.f,  xi = (dx + 1.f) * 31.f;
        float y0f = floorf(yi), x0f = floorf(xi);
        int iy = (int)y0f, ix = (int)x0f;
        float wy1 = yi - y0f, wx1 = xi - x0f;
        float wy0 = 1.f - wy1, wx0 = 1.f - wx1;
        if ((unsigned)iy > 62u)       wy0 = 0.f;
        if ((unsigned)(iy + 1) > 62u) wy1 = 0.f;
        if ((unsigned)ix > 62u)       wx0 = 0.f;
        if ((unsigned)(ix + 1) > 62u) wx1 = 0.f;
        int ry0 = min(max(iy, 0), 62) * 63;
        int ry1 = min(max(iy + 1, 0), 62) * 63;
        int cx0 = min(max(ix, 0), 62);
        int cx1 = min(max(ix + 1, 0), 62);
        float t00 = __half2float(rph[ry0 + cx0]), t01 = __half2float(rph[ry0 + cx1]);
        float t10 = __half2float(rph[ry1 + cx0]), t11 = __half2float(rph[ry1 + cx1]);
        float bias = wy0 * fmaf(wx0, t00, wx1 * t01)
                   + wy1 * fmaf(wx0, t10, wx1 * t11);

        // logits structurally small: exp without max tracking
        float p = __expf(dot + bias);
        l += p;

        const float* vr = vb2 + s * 32;   // wave-uniform -> s_load
#pragma unroll
        for (int c8 = 0; c8 < 4; ++c8) {
            const int o = c8 * 8;
            float v0 = vr[o + 0], v1 = vr[o + 1], v2 = vr[o + 2], v3 = vr[o + 3];
            float v4 = vr[o + 4], v5 = vr[o + 5], v6 = vr[o + 6], v7 = vr[o + 7];
            oacc[o + 0] = fmaf(p, v0, oacc[o + 0]); oacc[o + 1] = fmaf(p, v1, oacc[o + 1]);
            oacc[o + 2] = fmaf(p, v2, oacc[o + 2]); oacc[o + 3] = fmaf(p, v3, oacc[o + 3]);
            oacc[o + 4] = fmaf(p, v4, oacc[o + 4]); oacc[o + 5] = fmaf(p, v5, oacc[o + 5]);
            oacc[o + 6] = fmaf(p, v6, oacc[o + 6]); oacc[o + 7] = fmaf(p, v7, oacc[o + 7]);
        }
    }

    // ---- merge 8 sample-group waves: plain sums (rph/ps dead now) ----
    __syncthreads();
    float* lbuf = smem;                    // 512 floats
    float4* red = (float4*)(smem + 512);   // 512 float4
    lbuf[tid] = l;
    __syncthreads();
    float L = 0.f;
#pragma unroll
    for (int j = 0; j < 8; ++j) L += lbuf[q + 64 * j];
    float scale = 1.f / L;

    __half* ogh = aoT + ((size_t)(b * HWSZ + qidx)) * CC_ + h * HCH;
#pragma unroll
    for (int cb = 0; cb < 8; ++cb) {
        __syncthreads();
        red[tid] = make_float4(oacc[cb * 4 + 0] * scale, oacc[cb * 4 + 1] * scale,
                               oacc[cb * 4 + 2] * scale, oacc[cb * 4 + 3] * scale);
        __syncthreads();
        if (sgrp == 0) {
            float4 sm = red[q];
#pragma unroll
            for (int j = 1; j < 8; ++j) {
                float4 a = red[q + 64 * j];
                sm.x += a.x; sm.y += a.y; sm.z += a.z; sm.w += a.w;
            }
            __half2* d = (__half2*)(ogh + cb * 4);
            d[0] = __floats2half2_rn(sm.x, sm.y);
            d[1] = __floats2half2_rn(sm.z, sm.w);
        }
    }
}

extern "C" void kernel_launch(void* const* d_in, const int* in_sizes, int n_in,
                              void* d_out, int out_size, void* d_ws, size_t ws_size,
                              hipStream_t stream) {
    (void)in_sizes; (void)n_in; (void)out_size; (void)ws_size;
    const float* x   = (const float*)d_in[0];
    const float* Wq  = (const float*)d_in[1];
    const float* bq  = (const float*)d_in[2];
    const float* Wk  = (const float*)d_in[3];
    const float* bk  = (const float*)d_in[4];
    const float* Wv  = (const float*)d_in[5];
    const float* bv  = (const float*)d_in[6];
    const float* Wo  = (const float*)d_in[7];
    const float* bo  = (const float*)d_in[8];
    const float* dww = (const float*)d_in[9];
    const float* dwb = (const float*)d_in[10];
    const float* lng = (const float*)d_in[11];
    const float* lnb = (const float*)d_in[12];
    const float* pww = (const float*)d_in[13];
    const float* rpe = (const float*)d_in[14];
    float* out = (float*)d_out;

    // Workspace layout (float slots). xh/aoT = B*HWSZ*CC_ halfs = 786432 float
    // slots (aliased: xh dead after conv_q, attn fully overwrites as aoT).
    float* p = (float*)d_ws;
    float* qbuf  = p; p += 1572864;                 // fp32 [b][c][n]
    float* posb  = p; p += 12288;
    float* xsb   = p; p += 393216;                  // fp32 [b][c][s]
    __half* ktb  = (__half*)p; p += 196608;         // 393216 halfs: K fp16 [bh][s][32]
    float* vtb   = p; p += 393216;                  // V fp32 [bh][s][32]
    float* cobuf = p; p += 393216;
    __half* xh   = (__half*)p;                      // 1572864 halfs: [b][n][c]
    __half* aoT  = (__half*)p; p += 786432;         // aliases xh
    __half* wqh  = (__half*)p; p += 73728;          // 147456 halfs (CC_*CC_)
    __half* woh  = (__half*)p; p += 73728;
    __half* wkh  = (__half*)p; p += 73728;
    __half* wvh  = (__half*)p; p += 73728;
    __half* xsh  = (__half*)p; p += 196608;         // 393216 halfs: [b][s][c]
    // total: 4,239,360 floats = 16.96 MB (< 17.35 MB validated in R1-R8)

    cvt_f2h<<<dim3((CC_ * CC_ / 4 + 255) / 256), 256, 0, stream>>>(Wq, wqh, CC_ * CC_ / 4);
    cvt_f2h<<<dim3((CC_ * CC_ / 4 + 255) / 256), 256, 0, stream>>>(Wo, woh, CC_ * CC_ / 4);
    cvt_f2h<<<dim3((CC_ * CC_ / 4 + 255) / 256), 256, 0, stream>>>(Wk, wkh, CC_ * CC_ / 4);
    cvt_f2h<<<dim3((CC_ * CC_ / 4 + 255) / 256), 256, 0, stream>>>(Wv, wvh, CC_ * CC_ / 4);
    cvt_T_f2h<<<dim3(HWSZ / 64, CC_ / 64, BB), 256, 0, stream>>>(x, xh, CC_, HWSZ);
    conv1x1_mfma_h<CC_><<<dim3(HWSZ / 32, CC_ / 64, BB), 256, 0, stream>>>(wqh, bq, xh, qbuf, HWSZ, CC_);
    offset_dw_kernel<<<dim3(NGC_, 24), 256, 0, stream>>>(qbuf, dww, dwb, cobuf);
    offset_fin_kernel<<<dim3(1536), 256, 0, stream>>>(cobuf, lng, lnb, pww, posb);
    sample_xs_kernel<<<dim3(NGC_, 24), 256, 0, stream>>>(x, posb, xsb);
    cvt_T_f2h<<<dim3(NS_ / 64, CC_ / 64, BB), 256, 0, stream>>>(xsb, xsh, CC_, NS_);
    convkv_mfma<CC_><<<dim3(NS_ / 32, CC_ / 64, BB), 256, 0, stream>>>(wkh, bk, wvh, bv, xsh, ktb, vtb);
    attn_kernel<<<dim3(16, BB * NHD), 512, 0, stream>>>(qbuf, ktb, vtb, posb, rpe, aoT);
    conv1x1_mfma_h<CC_><<<dim3(HWSZ / 32, CC_ / 64, BB), 256, 0, stream>>>(woh, bo, aoT, out, HWSZ, CC_);
}

// Round 17
// 97.199 us; speedup vs baseline: 1.4000x; 1.1592x over previous
//
#include <hip/hip_runtime.h>
#include <hip/hip_bf16.h>
#include <hip/hip_fp16.h>

#define BB 4
#define CC_ 384
#define HH 32
#define WW 32
#define HWSZ 1024
#define NHD 12
#define HCH 32
#define GG 6
#define NGC_ 64
#define GHD 2
#define HK_ 16
#define WK_ 16
#define NS_ 256
#define RPEW 63
#define SCALE_ 0.17677669529663687f

typedef _Float16 half8_t __attribute__((ext_vector_type(8)));
typedef float f32x4_t __attribute__((ext_vector_type(4)));
typedef unsigned u32x4_t __attribute__((ext_vector_type(4)));

// ---------------- cvt: fp32 -> fp16 flat ----------------
__global__ void cvt_f2h(const float* __restrict__ src, __half* __restrict__ dst, int n4)
{
    int i = blockIdx.x * 256 + threadIdx.x;
    if (i < n4) {
        float4 v = *(const float4*)(src + (size_t)i * 4);
        __half2* d = (__half2*)(dst + (size_t)i * 4);
        d[0] = __floats2half2_rn(v.x, v.y);
        d[1] = __floats2half2_rn(v.z, v.w);
    }
}

// ---------------- cvt_T_f2h: X [b][c][n] fp32 -> XT [b][n][c] fp16 (LDS transpose) ----------------
__global__ void cvt_T_f2h(const float* __restrict__ X, __half* __restrict__ XT, int C, int N)
{
    __shared__ float tile[64][65];
    const int b = blockIdx.z;
    const int c0 = blockIdx.y * 64, n0 = blockIdx.x * 64;
    const int tid = threadIdx.x;
    const int tn = tid & 63, tg = tid >> 6;
#pragma unroll
    for (int k = 0; k < 16; ++k) {
        int r = k * 4 + tg;
        tile[r][tn] = X[((size_t)(b * C + c0 + r)) * N + n0 + tn];
    }
    __syncthreads();
    const int cp = tg * 16;
    __half hb[16] __attribute__((aligned(16)));
#pragma unroll
    for (int j = 0; j < 16; ++j) hb[j] = __float2half(tile[cp + j][tn]);
    __half* dst = XT + ((size_t)(b * N + n0 + tn)) * C + c0 + cp;
    *(uint4*)(dst) = *(uint4*)(hb);
    *(uint4*)(dst + 8) = *(uint4*)(hb + 8);
}

// ---------------- K6: MFMA fp16 conv1x1 (fp32 out) ----------------
template<int CIN>
__global__ __launch_bounds__(256)
void conv1x1_mfma_h(const __half* __restrict__ Wh, const float* __restrict__ bias,
                    const __half* __restrict__ XT, float* __restrict__ Y, int N, int OC)
{
    const int tid = threadIdx.x;
    const int wv = tid >> 6;
    const int lane = tid & 63;
    const int l15 = lane & 15, lhi = lane >> 4;
    const int otile = blockIdx.y * 64 + wv * 16;
    const int ntile = blockIdx.x * 32;
    const int b = blockIdx.z;

    const __half* Wp = Wh + (size_t)(otile + l15) * CIN + lhi * 8;
    const __half* Xp0 = XT + ((size_t)(b * N + ntile + l15)) * CIN + lhi * 8;
    const __half* Xp1 = Xp0 + (size_t)16 * CIN;

    f32x4_t acc0 = {0.f, 0.f, 0.f, 0.f}, acc1 = {0.f, 0.f, 0.f, 0.f};
#pragma unroll
    for (int k0 = 0; k0 < CIN; k0 += 32) {
        half8_t af = *(const half8_t*)(Wp + k0);
        half8_t b0 = *(const half8_t*)(Xp0 + k0);
        half8_t b1 = *(const half8_t*)(Xp1 + k0);
        acc0 = __builtin_amdgcn_mfma_f32_16x16x32_f16(af, b0, acc0, 0, 0, 0);
        acc1 = __builtin_amdgcn_mfma_f32_16x16x32_f16(af, b1, acc1, 0, 0, 0);
    }
#pragma unroll
    for (int r = 0; r < 4; ++r) {
        float bv = bias[otile + lhi * 4 + r];
        float* yr = Y + ((size_t)(b * OC + otile + lhi * 4 + r)) * N + ntile + l15;
        yr[0]  = acc0[r] + bv;
        yr[16] = acc1[r] + bv;
    }
}

// ---------------- K1: MFMA conv for q: fp32 [b][c][n] + fp16 SCALED [b][n][c] ----------------
__global__ __launch_bounds__(256)
void convq_mfma(const __half* __restrict__ Wh, const float* __restrict__ bias,
                const __half* __restrict__ XT, float* __restrict__ Y,
                __half* __restrict__ Qh)
{
    const int tid = threadIdx.x;
    const int wv = tid >> 6;
    const int lane = tid & 63;
    const int l15 = lane & 15, lhi = lane >> 4;
    const int otile = blockIdx.y * 64 + wv * 16;
    const int ntile = blockIdx.x * 32;
    const int b = blockIdx.z;

    const __half* Wp = Wh + (size_t)(otile + l15) * CC_ + lhi * 8;
    const __half* Xp0 = XT + ((size_t)(b * HWSZ + ntile + l15)) * CC_ + lhi * 8;
    const __half* Xp1 = Xp0 + (size_t)16 * CC_;

    f32x4_t acc0 = {0.f, 0.f, 0.f, 0.f}, acc1 = {0.f, 0.f, 0.f, 0.f};
#pragma unroll
    for (int k0 = 0; k0 < CC_; k0 += 32) {
        half8_t af = *(const half8_t*)(Wp + k0);
        half8_t b0 = *(const half8_t*)(Xp0 + k0);
        half8_t b1 = *(const half8_t*)(Xp1 + k0);
        acc0 = __builtin_amdgcn_mfma_f32_16x16x32_f16(af, b0, acc0, 0, 0, 0);
        acc1 = __builtin_amdgcn_mfma_f32_16x16x32_f16(af, b1, acc1, 0, 0, 0);
    }
    float bv[4];
#pragma unroll
    for (int r = 0; r < 4; ++r) bv[r] = bias[otile + lhi * 4 + r];
#pragma unroll
    for (int r = 0; r < 4; ++r) {
        float* yr = Y + ((size_t)(b * CC_ + otile + lhi * 4 + r)) * HWSZ + ntile + l15;
        yr[0]  = acc0[r] + bv[r];
        yr[16] = acc1[r] + bv[r];
    }
    // fp16 transposed + scaled copy for attention
    {
        int n0 = ntile + l15;
        __half2 h0 = __floats2half2_rn((acc0[0] + bv[0]) * SCALE_, (acc0[1] + bv[1]) * SCALE_);
        __half2 h1 = __floats2half2_rn((acc0[2] + bv[2]) * SCALE_, (acc0[3] + bv[3]) * SCALE_);
        uint2 u;
        u.x = __builtin_bit_cast(unsigned, h0);
        u.y = __builtin_bit_cast(unsigned, h1);
        *(uint2*)(Qh + ((size_t)(b * HWSZ + n0)) * CC_ + otile + lhi * 4) = u;
        h0 = __floats2half2_rn((acc1[0] + bv[0]) * SCALE_, (acc1[1] + bv[1]) * SCALE_);
        h1 = __floats2half2_rn((acc1[2] + bv[2]) * SCALE_, (acc1[3] + bv[3]) * SCALE_);
        u.x = __builtin_bit_cast(unsigned, h0);
        u.y = __builtin_bit_cast(unsigned, h1);
        *(uint2*)(Qh + ((size_t)(b * HWSZ + n0 + 16)) * CC_ + otile + lhi * 4) = u;
    }
}

// ---------------- K4: MFMA fused K+V conv; K fp16 [bh][s][32], V fp16 [bh][c][s] ----------------
template<int CIN>
__global__ __launch_bounds__(256)
void convkv_mfma(const __half* __restrict__ Wkh, const float* __restrict__ bk,
                 const __half* __restrict__ Wvh, const float* __restrict__ bv,
                 const __half* __restrict__ XS, __half* __restrict__ Yk,
                 __half* __restrict__ Yv)
{
    const int tid = threadIdx.x;
    const int wv = tid >> 6;
    const int lane = tid & 63;
    const int l15 = lane & 15, lhi = lane >> 4;
    const int otile = blockIdx.y * 64 + wv * 16;
    const int stile = blockIdx.x * 32;
    const int b = blockIdx.z;

    const __half* Wkp = Wkh + (size_t)(otile + l15) * CIN + lhi * 8;
    const __half* Wvp = Wvh + (size_t)(otile + l15) * CIN + lhi * 8;
    const __half* Xp0 = XS + ((size_t)(b * NS_ + stile + l15)) * CIN + lhi * 8;
    const __half* Xp1 = Xp0 + (size_t)16 * CIN;

    f32x4_t ka0 = {0.f,0.f,0.f,0.f}, ka1 = {0.f,0.f,0.f,0.f};
    f32x4_t va0 = {0.f,0.f,0.f,0.f}, va1 = {0.f,0.f,0.f,0.f};
#pragma unroll
    for (int c0 = 0; c0 < CIN; c0 += 32) {
        half8_t ak = *(const half8_t*)(Wkp + c0);
        half8_t av = *(const half8_t*)(Wvp + c0);
        half8_t b0 = *(const half8_t*)(Xp0 + c0);
        half8_t b1 = *(const half8_t*)(Xp1 + c0);
        ka0 = __builtin_amdgcn_mfma_f32_16x16x32_f16(ak, b0, ka0, 0, 0, 0);
        ka1 = __builtin_amdgcn_mfma_f32_16x16x32_f16(ak, b1, ka1, 0, 0, 0);
        va0 = __builtin_amdgcn_mfma_f32_16x16x32_f16(av, b0, va0, 0, 0, 0);
        va1 = __builtin_amdgcn_mfma_f32_16x16x32_f16(av, b1, va1, 0, 0, 0);
    }
    const int h = otile >> 5;
    const int c32 = (otile & 31) + lhi * 4;
    const size_t bh = (size_t)(b * NHD + h);
    float bkv[4], bvv[4];
#pragma unroll
    for (int r = 0; r < 4; ++r) {
        bkv[r] = bk[otile + lhi * 4 + r];
        bvv[r] = bv[otile + lhi * 4 + r];
    }
    // K: [bh][s][32]
    {
        size_t base = (bh * NS_ + stile + l15) * 32 + c32;
        __half2 kh[2];
        kh[0] = __floats2half2_rn(ka0[0] + bkv[0], ka0[1] + bkv[1]);
        kh[1] = __floats2half2_rn(ka0[2] + bkv[2], ka0[3] + bkv[3]);
        *(uint2*)(Yk + base) = *(uint2*)kh;
        base = (bh * NS_ + stile + 16 + l15) * 32 + c32;
        kh[0] = __floats2half2_rn(ka1[0] + bkv[0], ka1[1] + bkv[1]);
        kh[1] = __floats2half2_rn(ka1[2] + bkv[2], ka1[3] + bkv[3]);
        *(uint2*)(Yk + base) = *(uint2*)kh;
    }
    // V: [bh][c][s]  (c-major for attention PV A-frag half8 loads)
    {
        __half* vdst = Yv + (bh * 32 + c32) * NS_;
#pragma unroll
        for (int r = 0; r < 4; ++r) {
            vdst[(size_t)r * NS_ + stile + l15]      = __float2half(va0[r] + bvv[r]);
            vdst[(size_t)r * NS_ + stile + 16 + l15] = __float2half(va1[r] + bvv[r]);
        }
    }
}

// ---------------- K2a: depthwise conv 5x5 stride 2, transposed output [bg][pos][ch] ----------------
__global__ void offset_dw_kernel(const float* __restrict__ qb, const float* __restrict__ dww,
                                 const float* __restrict__ dwb, float* __restrict__ cobuf)
{
    __shared__ float img[HWSZ];
    const int c = blockIdx.x, bg = blockIdx.y;
    const int b = bg / GG, g = bg - b * GG;
    const int tid = threadIdx.x;
    const float* src = qb + ((size_t)(b * CC_ + g * NGC_ + c)) * HWSZ;
#pragma unroll
    for (int e = tid; e < HWSZ; e += 256) img[e] = src[e];
    __syncthreads();
    const int oy = tid >> 4, ox = tid & 15;
    float s = dwb[c];
    const float* wf = dww + c * 25;
    const int iy0 = oy * 2 - 2, ix0 = ox * 2 - 2;
#pragma unroll
    for (int ky = 0; ky < 5; ++ky) {
        int iy = iy0 + ky;
        if (iy < 0 || iy > 31) continue;
#pragma unroll
        for (int kx = 0; kx < 5; ++kx) {
            int ix = ix0 + kx;
            if (ix < 0 || ix > 31) continue;
            s = fmaf(img[iy * 32 + ix], wf[ky * 5 + kx], s);
        }
    }
    cobuf[((size_t)(bg * 256 + tid)) * NGC_ + c] = s;
}

// ---------------- K2b: LN + GELU + pw + tanh, one wave per position ----------------
__global__ void offset_fin_kernel(const float* __restrict__ cobuf, const float* __restrict__ lng,
                                  const float* __restrict__ lnb, const float* __restrict__ pww,
                                  float* __restrict__ posb)
{
    const int lane = threadIdx.x & 63;
    const int gpos = blockIdx.x * 4 + (threadIdx.x >> 6);
    const int bg = gpos >> 8, pos = gpos & 255;
    const int oy = (pos >> 4), ox = pos & 15;

    float v = cobuf[(size_t)gpos * NGC_ + lane];
    float s1 = v, s2 = v * v;
#pragma unroll
    for (int off = 32; off >= 1; off >>= 1) {
        s1 += __shfl_xor(s1, off);
        s2 += __shfl_xor(s2, off);
    }
    float mu = s1 * (1.f / 64.f);
    float var = s2 * (1.f / 64.f) - mu * mu;
    float rstd = rsqrtf(var + 1e-5f);
    float t = (v - mu) * rstd * lng[lane] + lnb[lane];
    float gv = 0.5f * t * (1.f + erff(t * 0.70710678118654752f));
    float o0 = pww[lane] * gv;
    float o1 = pww[64 + lane] * gv;
#pragma unroll
    for (int off = 32; off >= 1; off >>= 1) {
        o0 += __shfl_xor(o0, off);
        o1 += __shfl_xor(o1, off);
    }
    if (lane == 0) {
        float py = tanhf(o0) * (2.f / 15.f) + ((0.5f + (float)oy) * (1.f / 15.f)) * 2.f - 1.f;
        float px = tanhf(o1) * (2.f / 15.f) + ((0.5f + (float)ox) * (1.f / 15.f)) * 2.f - 1.f;
        posb[bg * 512 + pos * 2 + 0] = py;
        posb[bg * 512 + pos * 2 + 1] = px;
    }
}

// ---------------- K3: bilinear KV sampling ----------------
__global__ void sample_xs_kernel(const float* __restrict__ x, const float* __restrict__ posb,
                                 float* __restrict__ xsb)
{
    const int cc = blockIdx.x, bg = blockIdx.y;
    const int b = bg / GG, g = bg - b * GG;
    const int s = threadIdx.x;
    float py = posb[bg * 512 + s * 2 + 0];
    float px = posb[bg * 512 + s * 2 + 1];
    float xi = (px + 1.f) * 0.5f * 31.f;
    float yi = (py + 1.f) * 0.5f * 31.f;
    float x0f = floorf(xi), y0f = floorf(yi);
    int x0 = (int)x0f, y0 = (int)y0f;
    float wx1 = xi - x0f, wy1 = yi - y0f;
    const float* img = x + ((size_t)(b * CC_ + g * NGC_ + cc)) * HWSZ;
    float acc = 0.f;
#pragma unroll
    for (int t = 0; t < 4; ++t) {
        int iy = y0 + (t >> 1), ix = x0 + (t & 1);
        float w = ((t >> 1) ? wy1 : 1.f - wy1) * ((t & 1) ? wx1 : 1.f - wx1);
        if (iy >= 0 && iy <= 31 && ix >= 0 && ix <= 31)
            acc = fmaf(img[iy * 32 + ix], w, acc);
    }
    xsb[((size_t)(b * CC_ + g * NGC_ + cc)) * NS_ + s] = acc;
}

// ---------------- K5: full-MFMA attention ----------------
// grid (16 qtiles64, 48 bh), block 256 = 4 waves; wave = 16 q x 256 s.
// QK: S = mfma(K[16s x 32c], Q[16q x 32c]) -> lane: s=stile+lhi*4+r, q=l15.
// bias+exp per lane (4 pairs/tile); pack p to half2 words; shfl-exchange to
// PV B-frag; PV: O[c][q] = mfma(V[16c x 32s], P) x2 c-tiles, 8 chunks.
__launch_bounds__(256)
__global__ void attn_mfma(const __half* __restrict__ qh, const __half* __restrict__ kt,
                          const __half* __restrict__ vt, const float* __restrict__ posb,
                          const float* __restrict__ rpe, __half* __restrict__ aoT)
{
    __shared__ __half rph[4096];
    __shared__ float ps[512];
    const int bh = blockIdx.y;
    const int b = bh / NHD, h = bh - b * NHD;
    const int bg = b * GG + (h >> 1);
    const int tid = threadIdx.x;
    for (int e = tid; e < RPEW * RPEW; e += 256)
        rph[e] = __float2half(rpe[(size_t)h * (RPEW * RPEW) + e]);
    for (int e = tid; e < 512; e += 256) ps[e] = posb[bg * 512 + e];
    __syncthreads();

    const int wave = tid >> 6;
    const int lane = tid & 63;
    const int l15 = lane & 15, lhi = lane >> 4;
    const int qglob = blockIdx.x * 64 + wave * 16 + l15;
    const int row = qglob >> 5, col = qglob & 31;
    const float yc = ((float)row * (2.f / 31.f) - 1.f) * 15.5f + 31.f;
    const float xc = ((float)col * (2.f / 31.f) - 1.f) * 15.5f + 31.f;

    half8_t qf = *(const half8_t*)(qh + ((size_t)(b * HWSZ + qglob)) * CC_ + h * HCH + lhi * 8);

    const __half* kbase = kt + (size_t)bh * NS_ * 32;
    const __half* vbase = vt + (size_t)bh * 32 * NS_;

    f32x4_t oacc0 = {0.f,0.f,0.f,0.f}, oacc1 = {0.f,0.f,0.f,0.f};
    const f32x4_t zero4 = {0.f,0.f,0.f,0.f};
    float lsum = 0.f;

    for (int chunk = 0; chunk < 8; ++chunk) {
        const int sbase = chunk * 32;
        unsigned wa0 = 0, wa1 = 0, wb0 = 0, wb1 = 0;
#pragma unroll
        for (int t = 0; t < 2; ++t) {
            const int stile = sbase + t * 16;
            half8_t kf = *(const half8_t*)(kbase + (size_t)(stile + l15) * 32 + lhi * 8);
            f32x4_t sf = __builtin_amdgcn_mfma_f32_16x16x32_f16(kf, qf, zero4, 0, 0, 0);
            float pv[4];
#pragma unroll
            for (int r = 0; r < 4; ++r) {
                const int s = stile + lhi * 4 + r;
                float2 pp = *(const float2*)(ps + (s << 1));
                float yi = fmaf(pp.x, -15.5f, yc);
                float xi = fmaf(pp.y, -15.5f, xc);
                float y0f = floorf(yi), x0f = floorf(xi);
                int iy = (int)y0f, ix = (int)x0f;
                float wy1v = yi - y0f, wx1v = xi - x0f;
                float wy0v = 1.f - wy1v, wx0v = 1.f - wx1v;
                if ((unsigned)iy > 62u)       wy0v = 0.f;
                if ((unsigned)(iy + 1) > 62u) wy1v = 0.f;
                if ((unsigned)ix > 62u)       wx0v = 0.f;
                if ((unsigned)(ix + 1) > 62u) wx1v = 0.f;
                int ry0 = min(max(iy, 0), 62) * 63;
                int ry1 = min(max(iy + 1, 0), 62) * 63;
                int cx0 = min(max(ix, 0), 62);
                int cx1 = min(max(ix + 1, 0), 62);
                float t00 = __half2float(rph[ry0 + cx0]), t01 = __half2float(rph[ry0 + cx1]);
                float t10 = __half2float(rph[ry1 + cx0]), t11 = __half2float(rph[ry1 + cx1]);
                float bias = wy0v * fmaf(wx0v, t00, wx1v * t01)
                           + wy1v * fmaf(wx0v, t10, wx1v * t11);
                float p = __expf(sf[r] + bias);   // logits structurally small: no max
                lsum += p;
                pv[r] = p;
            }
            unsigned w0 = __builtin_bit_cast(unsigned, __floats2half2_rn(pv[0], pv[1]));
            unsigned w1 = __builtin_bit_cast(unsigned, __floats2half2_rn(pv[2], pv[3]));
            if (t == 0) { wa0 = w0; wa1 = w1; } else { wb0 = w0; wb1 = w1; }
        }
        // exchange packed P words into PV B-frag layout
        const int srcA = l15 + ((lhi & 1) << 5);
        const int srcB = srcA + 16;
        int g0a = __shfl((int)wa0, srcA), g0b = __shfl((int)wb0, srcA);
        int g1a = __shfl((int)wa1, srcA), g1b = __shfl((int)wb1, srcA);
        int g2a = __shfl((int)wa0, srcB), g2b = __shfl((int)wb0, srcB);
        int g3a = __shfl((int)wa1, srcB), g3b = __shfl((int)wb1, srcB);
        const bool hi = (lhi >= 2);
        u32x4_t bw;
        bw[0] = (unsigned)(hi ? g0b : g0a);
        bw[1] = (unsigned)(hi ? g1b : g1a);
        bw[2] = (unsigned)(hi ? g2b : g2a);
        bw[3] = (unsigned)(hi ? g3b : g3a);
        half8_t pf = __builtin_bit_cast(half8_t, bw);
        half8_t vf0 = *(const half8_t*)(vbase + (size_t)(l15) * NS_ + sbase + lhi * 8);
        half8_t vf1 = *(const half8_t*)(vbase + (size_t)(16 + l15) * NS_ + sbase + lhi * 8);
        oacc0 = __builtin_amdgcn_mfma_f32_16x16x32_f16(vf0, pf, oacc0, 0, 0, 0);
        oacc1 = __builtin_amdgcn_mfma_f32_16x16x32_f16(vf1, pf, oacc1, 0, 0, 0);
    }
    lsum += __shfl_xor(lsum, 16);
    lsum += __shfl_xor(lsum, 32);
    const float inv = 1.f / lsum;
    __half* og = aoT + ((size_t)(b * HWSZ + qglob)) * CC_ + h * HCH;
    {
        __half2 h0 = __floats2half2_rn(oacc0[0] * inv, oacc0[1] * inv);
        __half2 h1 = __floats2half2_rn(oacc0[2] * inv, oacc0[3] * inv);
        uint2 u;
        u.x = __builtin_bit_cast(unsigned, h0);
        u.y = __builtin_bit_cast(unsigned, h1);
        *(uint2*)(og + lhi * 4) = u;
        h0 = __floats2half2_rn(oacc1[0] * inv, oacc1[1] * inv);
        h1 = __floats2half2_rn(oacc1[2] * inv, oacc1[3] * inv);
        u.x = __builtin_bit_cast(unsigned, h0);
        u.y = __builtin_bit_cast(unsigned, h1);
        *(uint2*)(og + 16 + lhi * 4) = u;
    }
}

extern "C" void kernel_launch(void* const* d_in, const int* in_sizes, int n_in,
                              void* d_out, int out_size, void* d_ws, size_t ws_size,
                              hipStream_t stream) {
    (void)in_sizes; (void)n_in; (void)out_size; (void)ws_size;
    const float* x   = (const float*)d_in[0];
    const float* Wq  = (const float*)d_in[1];
    const float* bq  = (const float*)d_in[2];
    const float* Wk  = (const float*)d_in[3];
    const float* bk  = (const float*)d_in[4];
    const float* Wv  = (const float*)d_in[5];
    const float* bv  = (const float*)d_in[6];
    const float* Wo  = (const float*)d_in[7];
    const float* bo  = (const float*)d_in[8];
    const float* dww = (const float*)d_in[9];
    const float* dwb = (const float*)d_in[10];
    const float* lng = (const float*)d_in[11];
    const float* lnb = (const float*)d_in[12];
    const float* pww = (const float*)d_in[13];
    const float* rpe = (const float*)d_in[14];
    float* out = (float*)d_out;

    // Workspace (float slots), aliasing audited:
    //  R (786432): xh (steps cvt_xT..conv_q) -> cobuf=R[0:393216] (dw..fin),
    //              xsb=R[393216:] (sample..cvt_xs)
    //  qh (786432 = 1572864 halfs): written by conv_q, read by attn; attn writes
    //              aoT into the SAME per-block region it read -> alias qh==aoT.
    float* p = (float*)d_ws;
    float* qbuf  = p; p += 1572864;                 // fp32 [b][c][n]
    float* posb  = p; p += 12288;
    __half* ktb  = (__half*)p; p += 196608;         // K fp16 [bh][s][32]
    __half* vth  = (__half*)p; p += 196608;         // V fp16 [bh][c][s]
    float* R     = p; p += 786432;
    __half* xh   = (__half*)R;
    float* cobuf = R;
    float* xsb   = R + 393216;
    __half* qh   = (__half*)p; p += 786432;         // fp16 scaled [b][n][c]
    __half* aoT  = qh;                              // alias (see above)
    __half* wqh  = (__half*)p; p += 73728;
    __half* woh  = (__half*)p; p += 73728;
    __half* wkh  = (__half*)p; p += 73728;
    __half* wvh  = (__half*)p; p += 73728;
    __half* xsh  = (__half*)p; p += 196608;         // fp16 [b][s][c]
    // total 4,042,752 floats = 16.17 MB

    cvt_f2h<<<dim3((CC_ * CC_ / 4 + 255) / 256), 256, 0, stream>>>(Wq, wqh, CC_ * CC_ / 4);
    cvt_f2h<<<dim3((CC_ * CC_ / 4 + 255) / 256), 256, 0, stream>>>(Wo, woh, CC_ * CC_ / 4);
    cvt_f2h<<<dim3((CC_ * CC_ / 4 + 255) / 256), 256, 0, stream>>>(Wk, wkh, CC_ * CC_ / 4);
    cvt_f2h<<<dim3((CC_ * CC_ / 4 + 255) / 256), 256, 0, stream>>>(Wv, wvh, CC_ * CC_ / 4);
    cvt_T_f2h<<<dim3(HWSZ / 64, CC_ / 64, BB), 256, 0, stream>>>(x, xh, CC_, HWSZ);
    convq_mfma<<<dim3(HWSZ / 32, CC_ / 64, BB), 256, 0, stream>>>(wqh, bq, xh, qbuf, qh);
    offset_dw_kernel<<<dim3(NGC_, 24), 256, 0, stream>>>(qbuf, dww, dwb, cobuf);
    offset_fin_kernel<<<dim3(1536), 256, 0, stream>>>(cobuf, lng, lnb, pww, posb);
    sample_xs_kernel<<<dim3(NGC_, 24), 256, 0, stream>>>(x, posb, xsb);
    cvt_T_f2h<<<dim3(NS_ / 64, CC_ / 64, BB), 256, 0, stream>>>(xsb, xsh, CC_, NS_);
    convkv_mfma<CC_><<<dim3(NS_ / 32, CC_ / 64, BB), 256, 0, stream>>>(wkh, bk, wvh, bv, xsh, ktb, vth);
    attn_mfma<<<dim3(16, BB * NHD), 256, 0, stream>>>(qh, ktb, vth, posb, rpe, aoT);
    conv1x1_mfma_h<CC_><<<dim3(HWSZ / 32, CC_ / 64, BB), 256, 0, stream>>>(woh, bo, aoT, out, HWSZ, CC_);
}

// Round 18
// 88.961 us; speedup vs baseline: 1.5297x; 1.0926x over previous
//
#include <hip/hip_runtime.h>
#include <hip/hip_bf16.h>
#include <hip/hip_fp16.h>

#define BB 4
#define CC_ 384
#define HH 32
#define WW 32
#define HWSZ 1024
#define NHD 12
#define HCH 32
#define GG 6
#define NGC_ 64
#define GHD 2
#define HK_ 16
#define WK_ 16
#define NS_ 256
#define RPEW 63
#define SCALE_ 0.17677669529663687f

typedef _Float16 half8_t __attribute__((ext_vector_type(8)));
typedef float f32x4_t __attribute__((ext_vector_type(4)));
typedef unsigned u32x4_t __attribute__((ext_vector_type(4)));

// ---------------- cvt_w4: all four weight matrices fp32 -> fp16 in ONE launch ----------------
// grid: (144, 4); each matrix is CC_*CC_ = 147456 elems = 36864 float4
__global__ void cvt_w4(const float* __restrict__ w0, const float* __restrict__ w1,
                       const float* __restrict__ w2, const float* __restrict__ w3,
                       __half* __restrict__ o0, __half* __restrict__ o1,
                       __half* __restrict__ o2, __half* __restrict__ o3)
{
    const int m = blockIdx.y;
    const float* src = (m == 0) ? w0 : (m == 1) ? w1 : (m == 2) ? w2 : w3;
    __half* dst = (m == 0) ? o0 : (m == 1) ? o1 : (m == 2) ? o2 : o3;
    int i = blockIdx.x * 256 + threadIdx.x;
    if (i < CC_ * CC_ / 4) {
        float4 v = *(const float4*)(src + (size_t)i * 4);
        __half2* d = (__half2*)(dst + (size_t)i * 4);
        d[0] = __floats2half2_rn(v.x, v.y);
        d[1] = __floats2half2_rn(v.z, v.w);
    }
}

// ---------------- cvt_T_f2h: X [b][c][n] fp32 -> XT [b][n][c] fp16 (LDS transpose) ----------------
__global__ void cvt_T_f2h(const float* __restrict__ X, __half* __restrict__ XT, int C, int N)
{
    __shared__ float tile[64][65];
    const int b = blockIdx.z;
    const int c0 = blockIdx.y * 64, n0 = blockIdx.x * 64;
    const int tid = threadIdx.x;
    const int tn = tid & 63, tg = tid >> 6;
#pragma unroll
    for (int k = 0; k < 16; ++k) {
        int r = k * 4 + tg;
        tile[r][tn] = X[((size_t)(b * C + c0 + r)) * N + n0 + tn];
    }
    __syncthreads();
    const int cp = tg * 16;
    __half hb[16] __attribute__((aligned(16)));
#pragma unroll
    for (int j = 0; j < 16; ++j) hb[j] = __float2half(tile[cp + j][tn]);
    __half* dst = XT + ((size_t)(b * N + n0 + tn)) * C + c0 + cp;
    *(uint4*)(dst) = *(uint4*)(hb);
    *(uint4*)(dst + 8) = *(uint4*)(hb + 8);
}

// ---------------- K6: MFMA fp16 conv1x1 (fp32 out) ----------------
template<int CIN>
__global__ __launch_bounds__(256)
void conv1x1_mfma_h(const __half* __restrict__ Wh, const float* __restrict__ bias,
                    const __half* __restrict__ XT, float* __restrict__ Y, int N, int OC)
{
    const int tid = threadIdx.x;
    const int wv = tid >> 6;
    const int lane = tid & 63;
    const int l15 = lane & 15, lhi = lane >> 4;
    const int otile = blockIdx.y * 64 + wv * 16;
    const int ntile = blockIdx.x * 32;
    const int b = blockIdx.z;

    const __half* Wp = Wh + (size_t)(otile + l15) * CIN + lhi * 8;
    const __half* Xp0 = XT + ((size_t)(b * N + ntile + l15)) * CIN + lhi * 8;
    const __half* Xp1 = Xp0 + (size_t)16 * CIN;

    f32x4_t acc0 = {0.f, 0.f, 0.f, 0.f}, acc1 = {0.f, 0.f, 0.f, 0.f};
#pragma unroll
    for (int k0 = 0; k0 < CIN; k0 += 32) {
        half8_t af = *(const half8_t*)(Wp + k0);
        half8_t b0 = *(const half8_t*)(Xp0 + k0);
        half8_t b1 = *(const half8_t*)(Xp1 + k0);
        acc0 = __builtin_amdgcn_mfma_f32_16x16x32_f16(af, b0, acc0, 0, 0, 0);
        acc1 = __builtin_amdgcn_mfma_f32_16x16x32_f16(af, b1, acc1, 0, 0, 0);
    }
#pragma unroll
    for (int r = 0; r < 4; ++r) {
        float bv = bias[otile + lhi * 4 + r];
        float* yr = Y + ((size_t)(b * OC + otile + lhi * 4 + r)) * N + ntile + l15;
        yr[0]  = acc0[r] + bv;
        yr[16] = acc1[r] + bv;
    }
}

// ---------------- K1: MFMA conv for q: fp32 [b][c][n] + fp16 SCALED [b][n][c] ----------------
__global__ __launch_bounds__(256)
void convq_mfma(const __half* __restrict__ Wh, const float* __restrict__ bias,
                const __half* __restrict__ XT, float* __restrict__ Y,
                __half* __restrict__ Qh)
{
    const int tid = threadIdx.x;
    const int wv = tid >> 6;
    const int lane = tid & 63;
    const int l15 = lane & 15, lhi = lane >> 4;
    const int otile = blockIdx.y * 64 + wv * 16;
    const int ntile = blockIdx.x * 32;
    const int b = blockIdx.z;

    const __half* Wp = Wh + (size_t)(otile + l15) * CC_ + lhi * 8;
    const __half* Xp0 = XT + ((size_t)(b * HWSZ + ntile + l15)) * CC_ + lhi * 8;
    const __half* Xp1 = Xp0 + (size_t)16 * CC_;

    f32x4_t acc0 = {0.f, 0.f, 0.f, 0.f}, acc1 = {0.f, 0.f, 0.f, 0.f};
#pragma unroll
    for (int k0 = 0; k0 < CC_; k0 += 32) {
        half8_t af = *(const half8_t*)(Wp + k0);
        half8_t b0 = *(const half8_t*)(Xp0 + k0);
        half8_t b1 = *(const half8_t*)(Xp1 + k0);
        acc0 = __builtin_amdgcn_mfma_f32_16x16x32_f16(af, b0, acc0, 0, 0, 0);
        acc1 = __builtin_amdgcn_mfma_f32_16x16x32_f16(af, b1, acc1, 0, 0, 0);
    }
    float bv[4];
#pragma unroll
    for (int r = 0; r < 4; ++r) bv[r] = bias[otile + lhi * 4 + r];
#pragma unroll
    for (int r = 0; r < 4; ++r) {
        float* yr = Y + ((size_t)(b * CC_ + otile + lhi * 4 + r)) * HWSZ + ntile + l15;
        yr[0]  = acc0[r] + bv[r];
        yr[16] = acc1[r] + bv[r];
    }
    {
        int n0 = ntile + l15;
        __half2 h0 = __floats2half2_rn((acc0[0] + bv[0]) * SCALE_, (acc0[1] + bv[1]) * SCALE_);
        __half2 h1 = __floats2half2_rn((acc0[2] + bv[2]) * SCALE_, (acc0[3] + bv[3]) * SCALE_);
        uint2 u;
        u.x = __builtin_bit_cast(unsigned, h0);
        u.y = __builtin_bit_cast(unsigned, h1);
        *(uint2*)(Qh + ((size_t)(b * HWSZ + n0)) * CC_ + otile + lhi * 4) = u;
        h0 = __floats2half2_rn((acc1[0] + bv[0]) * SCALE_, (acc1[1] + bv[1]) * SCALE_);
        h1 = __floats2half2_rn((acc1[2] + bv[2]) * SCALE_, (acc1[3] + bv[3]) * SCALE_);
        u.x = __builtin_bit_cast(unsigned, h0);
        u.y = __builtin_bit_cast(unsigned, h1);
        *(uint2*)(Qh + ((size_t)(b * HWSZ + n0 + 16)) * CC_ + otile + lhi * 4) = u;
    }
}

// ---------------- K4: MFMA fused K+V conv; K fp16 [bh][s][32], V fp16 [bh][c][s] ----------------
template<int CIN>
__global__ __launch_bounds__(256)
void convkv_mfma(const __half* __restrict__ Wkh, const float* __restrict__ bk,
                 const __half* __restrict__ Wvh, const float* __restrict__ bv,
                 const __half* __restrict__ XS, __half* __restrict__ Yk,
                 __half* __restrict__ Yv)
{
    const int tid = threadIdx.x;
    const int wv = tid >> 6;
    const int lane = tid & 63;
    const int l15 = lane & 15, lhi = lane >> 4;
    const int otile = blockIdx.y * 64 + wv * 16;
    const int stile = blockIdx.x * 32;
    const int b = blockIdx.z;

    const __half* Wkp = Wkh + (size_t)(otile + l15) * CIN + lhi * 8;
    const __half* Wvp = Wvh + (size_t)(otile + l15) * CIN + lhi * 8;
    const __half* Xp0 = XS + ((size_t)(b * NS_ + stile + l15)) * CIN + lhi * 8;
    const __half* Xp1 = Xp0 + (size_t)16 * CIN;

    f32x4_t ka0 = {0.f,0.f,0.f,0.f}, ka1 = {0.f,0.f,0.f,0.f};
    f32x4_t va0 = {0.f,0.f,0.f,0.f}, va1 = {0.f,0.f,0.f,0.f};
#pragma unroll
    for (int c0 = 0; c0 < CIN; c0 += 32) {
        half8_t ak = *(const half8_t*)(Wkp + c0);
        half8_t av = *(const half8_t*)(Wvp + c0);
        half8_t b0 = *(const half8_t*)(Xp0 + c0);
        half8_t b1 = *(const half8_t*)(Xp1 + c0);
        ka0 = __builtin_amdgcn_mfma_f32_16x16x32_f16(ak, b0, ka0, 0, 0, 0);
        ka1 = __builtin_amdgcn_mfma_f32_16x16x32_f16(ak, b1, ka1, 0, 0, 0);
        va0 = __builtin_amdgcn_mfma_f32_16x16x32_f16(av, b0, va0, 0, 0, 0);
        va1 = __builtin_amdgcn_mfma_f32_16x16x32_f16(av, b1, va1, 0, 0, 0);
    }
    const int h = otile >> 5;
    const int c32 = (otile & 31) + lhi * 4;
    const size_t bh = (size_t)(b * NHD + h);
    float bkv[4], bvv[4];
#pragma unroll
    for (int r = 0; r < 4; ++r) {
        bkv[r] = bk[otile + lhi * 4 + r];
        bvv[r] = bv[otile + lhi * 4 + r];
    }
    {
        size_t base = (bh * NS_ + stile + l15) * 32 + c32;
        __half2 kh[2];
        kh[0] = __floats2half2_rn(ka0[0] + bkv[0], ka0[1] + bkv[1]);
        kh[1] = __floats2half2_rn(ka0[2] + bkv[2], ka0[3] + bkv[3]);
        *(uint2*)(Yk + base) = *(uint2*)kh;
        base = (bh * NS_ + stile + 16 + l15) * 32 + c32;
        kh[0] = __floats2half2_rn(ka1[0] + bkv[0], ka1[1] + bkv[1]);
        kh[1] = __floats2half2_rn(ka1[2] + bkv[2], ka1[3] + bkv[3]);
        *(uint2*)(Yk + base) = *(uint2*)kh;
    }
    {
        __half* vdst = Yv + (bh * 32 + c32) * NS_;
#pragma unroll
        for (int r = 0; r < 4; ++r) {
            vdst[(size_t)r * NS_ + stile + l15]      = __float2half(va0[r] + bvv[r]);
            vdst[(size_t)r * NS_ + stile + 16 + l15] = __float2half(va1[r] + bvv[r]);
        }
    }
}

// ---------------- K2a: depthwise conv 5x5 stride 2, transposed output [bg][pos][ch] ----------------
__global__ void offset_dw_kernel(const float* __restrict__ qb, const float* __restrict__ dww,
                                 const float* __restrict__ dwb, float* __restrict__ cobuf)
{
    __shared__ float img[HWSZ];
    const int c = blockIdx.x, bg = blockIdx.y;
    const int b = bg / GG, g = bg - b * GG;
    const int tid = threadIdx.x;
    const float* src = qb + ((size_t)(b * CC_ + g * NGC_ + c)) * HWSZ;
#pragma unroll
    for (int e = tid; e < HWSZ; e += 256) img[e] = src[e];
    __syncthreads();
    const int oy = tid >> 4, ox = tid & 15;
    float s = dwb[c];
    const float* wf = dww + c * 25;
    const int iy0 = oy * 2 - 2, ix0 = ox * 2 - 2;
#pragma unroll
    for (int ky = 0; ky < 5; ++ky) {
        int iy = iy0 + ky;
        if (iy < 0 || iy > 31) continue;
#pragma unroll
        for (int kx = 0; kx < 5; ++kx) {
            int ix = ix0 + kx;
            if (ix < 0 || ix > 31) continue;
            s = fmaf(img[iy * 32 + ix], wf[ky * 5 + kx], s);
        }
    }
    cobuf[((size_t)(bg * 256 + tid)) * NGC_ + c] = s;
}

// ---------------- K2b: LN + GELU + pw + tanh, one wave per position ----------------
__global__ void offset_fin_kernel(const float* __restrict__ cobuf, const float* __restrict__ lng,
                                  const float* __restrict__ lnb, const float* __restrict__ pww,
                                  float* __restrict__ posb)
{
    const int lane = threadIdx.x & 63;
    const int gpos = blockIdx.x * 4 + (threadIdx.x >> 6);
    const int bg = gpos >> 8, pos = gpos & 255;
    const int oy = (pos >> 4), ox = pos & 15;

    float v = cobuf[(size_t)gpos * NGC_ + lane];
    float s1 = v, s2 = v * v;
#pragma unroll
    for (int off = 32; off >= 1; off >>= 1) {
        s1 += __shfl_xor(s1, off);
        s2 += __shfl_xor(s2, off);
    }
    float mu = s1 * (1.f / 64.f);
    float var = s2 * (1.f / 64.f) - mu * mu;
    float rstd = rsqrtf(var + 1e-5f);
    float t = (v - mu) * rstd * lng[lane] + lnb[lane];
    float gv = 0.5f * t * (1.f + erff(t * 0.70710678118654752f));
    float o0 = pww[lane] * gv;
    float o1 = pww[64 + lane] * gv;
#pragma unroll
    for (int off = 32; off >= 1; off >>= 1) {
        o0 += __shfl_xor(o0, off);
        o1 += __shfl_xor(o1, off);
    }
    if (lane == 0) {
        float py = tanhf(o0) * (2.f / 15.f) + ((0.5f + (float)oy) * (1.f / 15.f)) * 2.f - 1.f;
        float px = tanhf(o1) * (2.f / 15.f) + ((0.5f + (float)ox) * (1.f / 15.f)) * 2.f - 1.f;
        posb[bg * 512 + pos * 2 + 0] = py;
        posb[bg * 512 + pos * 2 + 1] = px;
    }
}

// ---------------- K3: bilinear KV sampling ----------------
__global__ void sample_xs_kernel(const float* __restrict__ x, const float* __restrict__ posb,
                                 float* __restrict__ xsb)
{
    const int cc = blockIdx.x, bg = blockIdx.y;
    const int b = bg / GG, g = bg - b * GG;
    const int s = threadIdx.x;
    float py = posb[bg * 512 + s * 2 + 0];
    float px = posb[bg * 512 + s * 2 + 1];
    float xi = (px + 1.f) * 0.5f * 31.f;
    float yi = (py + 1.f) * 0.5f * 31.f;
    float x0f = floorf(xi), y0f = floorf(yi);
    int x0 = (int)x0f, y0 = (int)y0f;
    float wx1 = xi - x0f, wy1 = yi - y0f;
    const float* img = x + ((size_t)(b * CC_ + g * NGC_ + cc)) * HWSZ;
    float acc = 0.f;
#pragma unroll
    for (int t = 0; t < 4; ++t) {
        int iy = y0 + (t >> 1), ix = x0 + (t & 1);
        float w = ((t >> 1) ? wy1 : 1.f - wy1) * ((t & 1) ? wx1 : 1.f - wx1);
        if (iy >= 0 && iy <= 31 && ix >= 0 && ix <= 31)
            acc = fmaf(img[iy * 32 + ix], w, acc);
    }
    xsb[((size_t)(b * CC_ + g * NGC_ + cc)) * NS_ + s] = acc;
}

// ---------------- K5: full-MFMA attention with y-axis LDS table ----------------
// grid (16 qtiles64, 48 bh), block 256 = 4 waves; wave = 16 q x 256 s.
// Block covers rows {2*bx, 2*bx+1}; ytab[rr][s] = {ry0*63, ry1*63, half2(wy0,wy1), 15.5*px}.
__launch_bounds__(256)
__global__ void attn_mfma(const __half* __restrict__ qh, const __half* __restrict__ kt,
                          const __half* __restrict__ vt, const float* __restrict__ posb,
                          const float* __restrict__ rpe, __half* __restrict__ aoT)
{
    __shared__ __half rph[4096];
    __shared__ float4 ytab[512];
    const int bh = blockIdx.y;
    const int b = bh / NHD, h = bh - b * NHD;
    const int bg = b * GG + (h >> 1);
    const int tid = threadIdx.x;
    for (int e = tid; e < RPEW * RPEW; e += 256)
        rph[e] = __float2half(rpe[(size_t)h * (RPEW * RPEW) + e]);
    const int base_row = blockIdx.x * 2;
    for (int e = tid; e < 512; e += 256) {
        int rr = e >> 8, s = e & 255;
        float py = posb[bg * 512 + s * 2 + 0];
        float px = posb[bg * 512 + s * 2 + 1];
        float ycr = ((float)(base_row + rr) * (2.f / 31.f) - 1.f) * 15.5f + 31.f;
        float yi = fmaf(py, -15.5f, ycr);
        float y0f = floorf(yi);
        int iy = (int)y0f;
        float wy1 = yi - y0f, wy0 = 1.f - wy1;
        if ((unsigned)iy > 62u)       wy0 = 0.f;
        if ((unsigned)(iy + 1) > 62u) wy1 = 0.f;
        int ry0 = min(max(iy, 0), 62) * 63;
        int ry1 = min(max(iy + 1, 0), 62) * 63;
        float4 t;
        t.x = __int_as_float(ry0);
        t.y = __int_as_float(ry1);
        t.z = __uint_as_float(__builtin_bit_cast(unsigned, __floats2half2_rn(wy0, wy1)));
        t.w = px * 15.5f;
        ytab[rr * 256 + s] = t;
    }
    __syncthreads();

    const int wave = tid >> 6;
    const int lane = tid & 63;
    const int l15 = lane & 15, lhi = lane >> 4;
    const int qglob = blockIdx.x * 64 + wave * 16 + l15;
    const int col = qglob & 31;
    const float xc = ((float)col * (2.f / 31.f) - 1.f) * 15.5f + 31.f;
    const int rowl = wave >> 1;           // wave-uniform: row within block

    half8_t qf = *(const half8_t*)(qh + ((size_t)(b * HWSZ + qglob)) * CC_ + h * HCH + lhi * 8);

    const __half* kbase = kt + (size_t)bh * NS_ * 32;
    const __half* vbase = vt + (size_t)bh * 32 * NS_;

    f32x4_t oacc0 = {0.f,0.f,0.f,0.f}, oacc1 = {0.f,0.f,0.f,0.f};
    const f32x4_t zero4 = {0.f,0.f,0.f,0.f};
    float lsum = 0.f;

    for (int chunk = 0; chunk < 8; ++chunk) {
        const int sbase = chunk * 32;
        unsigned wa0 = 0, wa1 = 0, wb0 = 0, wb1 = 0;
#pragma unroll
        for (int t = 0; t < 2; ++t) {
            const int stile = sbase + t * 16;
            half8_t kf = *(const half8_t*)(kbase + (size_t)(stile + l15) * 32 + lhi * 8);
            f32x4_t sf = __builtin_amdgcn_mfma_f32_16x16x32_f16(kf, qf, zero4, 0, 0, 0);
            float pv[4];
#pragma unroll
            for (int r = 0; r < 4; ++r) {
                const int s = stile + lhi * 4 + r;
                float4 yt = ytab[rowl * 256 + s];
                int ry0 = __float_as_int(yt.x), ry1 = __float_as_int(yt.y);
                __half2 wyh = __builtin_bit_cast(__half2, __float_as_uint(yt.z));
                float wy0 = __low2float(wyh), wy1 = __high2float(wyh);
                float xi = xc - yt.w;
                float x0f = floorf(xi);
                int ix = (int)x0f;
                float wx1 = xi - x0f, wx0 = 1.f - wx1;
                if ((unsigned)ix > 62u)       wx0 = 0.f;
                if ((unsigned)(ix + 1) > 62u) wx1 = 0.f;
                int cx0 = min(max(ix, 0), 62);
                int cx1 = min(max(ix + 1, 0), 62);
                float t00 = __half2float(rph[ry0 + cx0]), t01 = __half2float(rph[ry0 + cx1]);
                float t10 = __half2float(rph[ry1 + cx0]), t11 = __half2float(rph[ry1 + cx1]);
                float bias = wy0 * fmaf(wx0, t00, wx1 * t01)
                           + wy1 * fmaf(wx0, t10, wx1 * t11);
                float p = __expf(sf[r] + bias);   // logits structurally small: no max
                lsum += p;
                pv[r] = p;
            }
            unsigned w0 = __builtin_bit_cast(unsigned, __floats2half2_rn(pv[0], pv[1]));
            unsigned w1 = __builtin_bit_cast(unsigned, __floats2half2_rn(pv[2], pv[3]));
            if (t == 0) { wa0 = w0; wa1 = w1; } else { wb0 = w0; wb1 = w1; }
        }
        const int srcA = l15 + ((lhi & 1) << 5);
        const int srcB = srcA + 16;
        int g0a = __shfl((int)wa0, srcA), g0b = __shfl((int)wb0, srcA);
        int g1a = __shfl((int)wa1, srcA), g1b = __shfl((int)wb1, srcA);
        int g2a = __shfl((int)wa0, srcB), g2b = __shfl((int)wb0, srcB);
        int g3a = __shfl((int)wa1, srcB), g3b = __shfl((int)wb1, srcB);
        const bool hi = (lhi >= 2);
        u32x4_t bw;
        bw[0] = (unsigned)(hi ? g0b : g0a);
        bw[1] = (unsigned)(hi ? g1b : g1a);
        bw[2] = (unsigned)(hi ? g2b : g2a);
        bw[3] = (unsigned)(hi ? g3b : g3a);
        half8_t pf = __builtin_bit_cast(half8_t, bw);
        half8_t vf0 = *(const half8_t*)(vbase + (size_t)(l15) * NS_ + sbase + lhi * 8);
        half8_t vf1 = *(const half8_t*)(vbase + (size_t)(16 + l15) * NS_ + sbase + lhi * 8);
        oacc0 = __builtin_amdgcn_mfma_f32_16x16x32_f16(vf0, pf, oacc0, 0, 0, 0);
        oacc1 = __builtin_amdgcn_mfma_f32_16x16x32_f16(vf1, pf, oacc1, 0, 0, 0);
    }
    lsum += __shfl_xor(lsum, 16);
    lsum += __shfl_xor(lsum, 32);
    const float inv = 1.f / lsum;
    __half* og = aoT + ((size_t)(b * HWSZ + qglob)) * CC_ + h * HCH;
    {
        __half2 h0 = __floats2half2_rn(oacc0[0] * inv, oacc0[1] * inv);
        __half2 h1 = __floats2half2_rn(oacc0[2] * inv, oacc0[3] * inv);
        uint2 u;
        u.x = __builtin_bit_cast(unsigned, h0);
        u.y = __builtin_bit_cast(unsigned, h1);
        *(uint2*)(og + lhi * 4) = u;
        h0 = __floats2half2_rn(oacc1[0] * inv, oacc1[1] * inv);
        h1 = __floats2half2_rn(oacc1[2] * inv, oacc1[3] * inv);
        u.x = __builtin_bit_cast(unsigned, h0);
        u.y = __builtin_bit_cast(unsigned, h1);
        *(uint2*)(og + 16 + lhi * 4) = u;
    }
}

extern "C" void kernel_launch(void* const* d_in, const int* in_sizes, int n_in,
                              void* d_out, int out_size, void* d_ws, size_t ws_size,
                              hipStream_t stream) {
    (void)in_sizes; (void)n_in; (void)out_size; (void)ws_size;
    const float* x   = (const float*)d_in[0];
    const float* Wq  = (const float*)d_in[1];
    const float* bq  = (const float*)d_in[2];
    const float* Wk  = (const float*)d_in[3];
    const float* bk  = (const float*)d_in[4];
    const float* Wv  = (const float*)d_in[5];
    const float* bv  = (const float*)d_in[6];
    const float* Wo  = (const float*)d_in[7];
    const float* bo  = (const float*)d_in[8];
    const float* dww = (const float*)d_in[9];
    const float* dwb = (const float*)d_in[10];
    const float* lng = (const float*)d_in[11];
    const float* lnb = (const float*)d_in[12];
    const float* pww = (const float*)d_in[13];
    const float* rpe = (const float*)d_in[14];
    float* out = (float*)d_out;

    // Workspace (float slots); aliasing audited (R16-validated layout):
    //  R (786432): xh (cvt_xT..conv_q) -> cobuf=R[0:393216], xsb=R[393216:]
    //  qh == aoT alias (attn reads/writes same per-block region)
    float* p = (float*)d_ws;
    float* qbuf  = p; p += 1572864;                 // fp32 [b][c][n]
    float* posb  = p; p += 12288;
    __half* ktb  = (__half*)p; p += 196608;         // K fp16 [bh][s][32]
    __half* vth  = (__half*)p; p += 196608;         // V fp16 [bh][c][s]
    float* R     = p; p += 786432;
    __half* xh   = (__half*)R;
    float* cobuf = R;
    float* xsb   = R + 393216;
    __half* qh   = (__half*)p; p += 786432;         // fp16 scaled [b][n][c]
    __half* aoT  = qh;
    __half* wqh  = (__half*)p; p += 73728;
    __half* woh  = (__half*)p; p += 73728;
    __half* wkh  = (__half*)p; p += 73728;
    __half* wvh  = (__half*)p; p += 73728;
    __half* xsh  = (__half*)p; p += 196608;         // fp16 [b][s][c]

    cvt_w4<<<dim3((CC_ * CC_ / 4 + 255) / 256, 4), 256, 0, stream>>>(Wq, Wo, Wk, Wv, wqh, woh, wkh, wvh);
    cvt_T_f2h<<<dim3(HWSZ / 64, CC_ / 64, BB), 256, 0, stream>>>(x, xh, CC_, HWSZ);
    convq_mfma<<<dim3(HWSZ / 32, CC_ / 64, BB), 256, 0, stream>>>(wqh, bq, xh, qbuf, qh);
    offset_dw_kernel<<<dim3(NGC_, 24), 256, 0, stream>>>(qbuf, dww, dwb, cobuf);
    offset_fin_kernel<<<dim3(1536), 256, 0, stream>>>(cobuf, lng, lnb, pww, posb);
    sample_xs_kernel<<<dim3(NGC_, 24), 256, 0, stream>>>(x, posb, xsb);
    cvt_T_f2h<<<dim3(NS_ / 64, CC_ / 64, BB), 256, 0, stream>>>(xsb, xsh, CC_, NS_);
    convkv_mfma<CC_><<<dim3(NS_ / 32, CC_ / 64, BB), 256, 0, stream>>>(wkh, bk, wvh, bv, xsh, ktb, vth);
    attn_mfma<<<dim3(16, BB * NHD), 256, 0, stream>>>(qh, ktb, vth, posb, rpe, aoT);
    conv1x1_mfma_h<CC_><<<dim3(HWSZ / 32, CC_ / 64, BB), 256, 0, stream>>>(woh, bo, aoT, out, HWSZ, CC_);
}

// Round 19
// 83.979 us; speedup vs baseline: 1.6204x; 1.0593x over previous
//
#include <hip/hip_runtime.h>
#include <hip/hip_bf16.h>
#include <hip/hip_fp16.h>

#define BB 4
#define CC_ 384
#define HH 32
#define WW 32
#define HWSZ 1024
#define NHD 12
#define HCH 32
#define GG 6
#define NGC_ 64
#define GHD 2
#define HK_ 16
#define WK_ 16
#define NS_ 256
#define RPEW 63
#define SCALE_ 0.17677669529663687f

typedef _Float16 half8_t __attribute__((ext_vector_type(8)));
typedef float f32x4_t __attribute__((ext_vector_type(4)));
typedef unsigned u32x4_t __attribute__((ext_vector_type(4)));

// ---------------- prep: 4x weight cvt + x transpose in ONE launch ----------------
// grid: 960 blocks. [0,576): weight fp32->fp16 (m = bid/144). [576,960): x [b][c][n] -> xh [b][n][c].
__global__ __launch_bounds__(256)
void prep_kernel(const float* __restrict__ w0, const float* __restrict__ w1,
                 const float* __restrict__ w2, const float* __restrict__ w3,
                 __half* __restrict__ o0, __half* __restrict__ o1,
                 __half* __restrict__ o2, __half* __restrict__ o3,
                 const float* __restrict__ X, __half* __restrict__ XT)
{
    __shared__ float tile[64][65];
    const int bid = blockIdx.x;
    const int tid = threadIdx.x;
    if (bid < 576) {
        const int m = bid / 144;
        const float* src = (m == 0) ? w0 : (m == 1) ? w1 : (m == 2) ? w2 : w3;
        __half* dst = (m == 0) ? o0 : (m == 1) ? o1 : (m == 2) ? o2 : o3;
        int i = (bid - m * 144) * 256 + tid;
        if (i < CC_ * CC_ / 4) {
            float4 v = *(const float4*)(src + (size_t)i * 4);
            __half2* d = (__half2*)(dst + (size_t)i * 4);
            d[0] = __floats2half2_rn(v.x, v.y);
            d[1] = __floats2half2_rn(v.z, v.w);
        }
    } else {
        const int t = bid - 576;
        const int n0 = (t & 15) * 64;
        const int c0 = ((t >> 4) % 6) * 64;
        const int b = t / 96;
        const int tn = tid & 63, tg = tid >> 6;
#pragma unroll
        for (int k = 0; k < 16; ++k) {
            int r = k * 4 + tg;
            tile[r][tn] = X[((size_t)(b * CC_ + c0 + r)) * HWSZ + n0 + tn];
        }
        __syncthreads();
        const int cp = tg * 16;
        __half hb[16] __attribute__((aligned(16)));
#pragma unroll
        for (int j = 0; j < 16; ++j) hb[j] = __float2half(tile[cp + j][tn]);
        __half* dst = XT + ((size_t)(b * HWSZ + n0 + tn)) * CC_ + c0 + cp;
        *(uint4*)(dst) = *(uint4*)(hb);
        *(uint4*)(dst + 8) = *(uint4*)(hb + 8);
    }
}

// ---------------- K6: MFMA fp16 conv1x1 (fp32 out) ----------------
template<int CIN>
__global__ __launch_bounds__(256)
void conv1x1_mfma_h(const __half* __restrict__ Wh, const float* __restrict__ bias,
                    const __half* __restrict__ XT, float* __restrict__ Y, int N, int OC)
{
    const int tid = threadIdx.x;
    const int wv = tid >> 6;
    const int lane = tid & 63;
    const int l15 = lane & 15, lhi = lane >> 4;
    const int otile = blockIdx.y * 64 + wv * 16;
    const int ntile = blockIdx.x * 32;
    const int b = blockIdx.z;

    const __half* Wp = Wh + (size_t)(otile + l15) * CIN + lhi * 8;
    const __half* Xp0 = XT + ((size_t)(b * N + ntile + l15)) * CIN + lhi * 8;
    const __half* Xp1 = Xp0 + (size_t)16 * CIN;

    f32x4_t acc0 = {0.f, 0.f, 0.f, 0.f}, acc1 = {0.f, 0.f, 0.f, 0.f};
#pragma unroll
    for (int k0 = 0; k0 < CIN; k0 += 32) {
        half8_t af = *(const half8_t*)(Wp + k0);
        half8_t b0 = *(const half8_t*)(Xp0 + k0);
        half8_t b1 = *(const half8_t*)(Xp1 + k0);
        acc0 = __builtin_amdgcn_mfma_f32_16x16x32_f16(af, b0, acc0, 0, 0, 0);
        acc1 = __builtin_amdgcn_mfma_f32_16x16x32_f16(af, b1, acc1, 0, 0, 0);
    }
#pragma unroll
    for (int r = 0; r < 4; ++r) {
        float bv = bias[otile + lhi * 4 + r];
        float* yr = Y + ((size_t)(b * OC + otile + lhi * 4 + r)) * N + ntile + l15;
        yr[0]  = acc0[r] + bv;
        yr[16] = acc1[r] + bv;
    }
}

// ---------------- K1: MFMA conv for q: fp32 [b][c][n] + fp16 SCALED [b][n][c] ----------------
__global__ __launch_bounds__(256)
void convq_mfma(const __half* __restrict__ Wh, const float* __restrict__ bias,
                const __half* __restrict__ XT, float* __restrict__ Y,
                __half* __restrict__ Qh)
{
    const int tid = threadIdx.x;
    const int wv = tid >> 6;
    const int lane = tid & 63;
    const int l15 = lane & 15, lhi = lane >> 4;
    const int otile = blockIdx.y * 64 + wv * 16;
    const int ntile = blockIdx.x * 32;
    const int b = blockIdx.z;

    const __half* Wp = Wh + (size_t)(otile + l15) * CC_ + lhi * 8;
    const __half* Xp0 = XT + ((size_t)(b * HWSZ + ntile + l15)) * CC_ + lhi * 8;
    const __half* Xp1 = Xp0 + (size_t)16 * CC_;

    f32x4_t acc0 = {0.f, 0.f, 0.f, 0.f}, acc1 = {0.f, 0.f, 0.f, 0.f};
#pragma unroll
    for (int k0 = 0; k0 < CC_; k0 += 32) {
        half8_t af = *(const half8_t*)(Wp + k0);
        half8_t b0 = *(const half8_t*)(Xp0 + k0);
        half8_t b1 = *(const half8_t*)(Xp1 + k0);
        acc0 = __builtin_amdgcn_mfma_f32_16x16x32_f16(af, b0, acc0, 0, 0, 0);
        acc1 = __builtin_amdgcn_mfma_f32_16x16x32_f16(af, b1, acc1, 0, 0, 0);
    }
    float bv[4];
#pragma unroll
    for (int r = 0; r < 4; ++r) bv[r] = bias[otile + lhi * 4 + r];
#pragma unroll
    for (int r = 0; r < 4; ++r) {
        float* yr = Y + ((size_t)(b * CC_ + otile + lhi * 4 + r)) * HWSZ + ntile + l15;
        yr[0]  = acc0[r] + bv[r];
        yr[16] = acc1[r] + bv[r];
    }
    {
        int n0 = ntile + l15;
        __half2 h0 = __floats2half2_rn((acc0[0] + bv[0]) * SCALE_, (acc0[1] + bv[1]) * SCALE_);
        __half2 h1 = __floats2half2_rn((acc0[2] + bv[2]) * SCALE_, (acc0[3] + bv[3]) * SCALE_);
        uint2 u;
        u.x = __builtin_bit_cast(unsigned, h0);
        u.y = __builtin_bit_cast(unsigned, h1);
        *(uint2*)(Qh + ((size_t)(b * HWSZ + n0)) * CC_ + otile + lhi * 4) = u;
        h0 = __floats2half2_rn((acc1[0] + bv[0]) * SCALE_, (acc1[1] + bv[1]) * SCALE_);
        h1 = __floats2half2_rn((acc1[2] + bv[2]) * SCALE_, (acc1[3] + bv[3]) * SCALE_);
        u.x = __builtin_bit_cast(unsigned, h0);
        u.y = __builtin_bit_cast(unsigned, h1);
        *(uint2*)(Qh + ((size_t)(b * HWSZ + n0 + 16)) * CC_ + otile + lhi * 4) = u;
    }
}

// ---------------- K4: MFMA fused K+V conv; K fp16 [bh][s][32], V fp16 [bh][c][s] ----------------
template<int CIN>
__global__ __launch_bounds__(256)
void convkv_mfma(const __half* __restrict__ Wkh, const float* __restrict__ bk,
                 const __half* __restrict__ Wvh, const float* __restrict__ bv,
                 const __half* __restrict__ XS, __half* __restrict__ Yk,
                 __half* __restrict__ Yv)
{
    const int tid = threadIdx.x;
    const int wv = tid >> 6;
    const int lane = tid & 63;
    const int l15 = lane & 15, lhi = lane >> 4;
    const int otile = blockIdx.y * 64 + wv * 16;
    const int stile = blockIdx.x * 32;
    const int b = blockIdx.z;

    const __half* Wkp = Wkh + (size_t)(otile + l15) * CIN + lhi * 8;
    const __half* Wvp = Wvh + (size_t)(otile + l15) * CIN + lhi * 8;
    const __half* Xp0 = XS + ((size_t)(b * NS_ + stile + l15)) * CIN + lhi * 8;
    const __half* Xp1 = Xp0 + (size_t)16 * CIN;

    f32x4_t ka0 = {0.f,0.f,0.f,0.f}, ka1 = {0.f,0.f,0.f,0.f};
    f32x4_t va0 = {0.f,0.f,0.f,0.f}, va1 = {0.f,0.f,0.f,0.f};
#pragma unroll
    for (int c0 = 0; c0 < CIN; c0 += 32) {
        half8_t ak = *(const half8_t*)(Wkp + c0);
        half8_t av = *(const half8_t*)(Wvp + c0);
        half8_t b0 = *(const half8_t*)(Xp0 + c0);
        half8_t b1 = *(const half8_t*)(Xp1 + c0);
        ka0 = __builtin_amdgcn_mfma_f32_16x16x32_f16(ak, b0, ka0, 0, 0, 0);
        ka1 = __builtin_amdgcn_mfma_f32_16x16x32_f16(ak, b1, ka1, 0, 0, 0);
        va0 = __builtin_amdgcn_mfma_f32_16x16x32_f16(av, b0, va0, 0, 0, 0);
        va1 = __builtin_amdgcn_mfma_f32_16x16x32_f16(av, b1, va1, 0, 0, 0);
    }
    const int h = otile >> 5;
    const int c32 = (otile & 31) + lhi * 4;
    const size_t bh = (size_t)(b * NHD + h);
    float bkv[4], bvv[4];
#pragma unroll
    for (int r = 0; r < 4; ++r) {
        bkv[r] = bk[otile + lhi * 4 + r];
        bvv[r] = bv[otile + lhi * 4 + r];
    }
    {
        size_t base = (bh * NS_ + stile + l15) * 32 + c32;
        __half2 kh[2];
        kh[0] = __floats2half2_rn(ka0[0] + bkv[0], ka0[1] + bkv[1]);
        kh[1] = __floats2half2_rn(ka0[2] + bkv[2], ka0[3] + bkv[3]);
        *(uint2*)(Yk + base) = *(uint2*)kh;
        base = (bh * NS_ + stile + 16 + l15) * 32 + c32;
        kh[0] = __floats2half2_rn(ka1[0] + bkv[0], ka1[1] + bkv[1]);
        kh[1] = __floats2half2_rn(ka1[2] + bkv[2], ka1[3] + bkv[3]);
        *(uint2*)(Yk + base) = *(uint2*)kh;
    }
    {
        __half* vdst = Yv + (bh * 32 + c32) * NS_;
#pragma unroll
        for (int r = 0; r < 4; ++r) {
            vdst[(size_t)r * NS_ + stile + l15]      = __float2half(va0[r] + bvv[r]);
            vdst[(size_t)r * NS_ + stile + 16 + l15] = __float2half(va1[r] + bvv[r]);
        }
    }
}

// ---------------- K2a: depthwise conv 5x5 stride 2, transposed output [bg][pos][ch] ----------------
__global__ void offset_dw_kernel(const float* __restrict__ qb, const float* __restrict__ dww,
                                 const float* __restrict__ dwb, float* __restrict__ cobuf)
{
    __shared__ float img[HWSZ];
    const int c = blockIdx.x, bg = blockIdx.y;
    const int b = bg / GG, g = bg - b * GG;
    const int tid = threadIdx.x;
    const float* src = qb + ((size_t)(b * CC_ + g * NGC_ + c)) * HWSZ;
#pragma unroll
    for (int e = tid; e < HWSZ; e += 256) img[e] = src[e];
    __syncthreads();
    const int oy = tid >> 4, ox = tid & 15;
    float s = dwb[c];
    const float* wf = dww + c * 25;
    const int iy0 = oy * 2 - 2, ix0 = ox * 2 - 2;
#pragma unroll
    for (int ky = 0; ky < 5; ++ky) {
        int iy = iy0 + ky;
        if (iy < 0 || iy > 31) continue;
#pragma unroll
        for (int kx = 0; kx < 5; ++kx) {
            int ix = ix0 + kx;
            if (ix < 0 || ix > 31) continue;
            s = fmaf(img[iy * 32 + ix], wf[ky * 5 + kx], s);
        }
    }
    cobuf[((size_t)(bg * 256 + tid)) * NGC_ + c] = s;
}

// ---------------- K2b: LN + GELU + pw + tanh, one wave per position ----------------
__global__ void offset_fin_kernel(const float* __restrict__ cobuf, const float* __restrict__ lng,
                                  const float* __restrict__ lnb, const float* __restrict__ pww,
                                  float* __restrict__ posb)
{
    const int lane = threadIdx.x & 63;
    const int gpos = blockIdx.x * 4 + (threadIdx.x >> 6);
    const int bg = gpos >> 8, pos = gpos & 255;
    const int oy = (pos >> 4), ox = pos & 15;

    float v = cobuf[(size_t)gpos * NGC_ + lane];
    float s1 = v, s2 = v * v;
#pragma unroll
    for (int off = 32; off >= 1; off >>= 1) {
        s1 += __shfl_xor(s1, off);
        s2 += __shfl_xor(s2, off);
    }
    float mu = s1 * (1.f / 64.f);
    float var = s2 * (1.f / 64.f) - mu * mu;
    float rstd = rsqrtf(var + 1e-5f);
    float t = (v - mu) * rstd * lng[lane] + lnb[lane];
    float gv = 0.5f * t * (1.f + erff(t * 0.70710678118654752f));
    float o0 = pww[lane] * gv;
    float o1 = pww[64 + lane] * gv;
#pragma unroll
    for (int off = 32; off >= 1; off >>= 1) {
        o0 += __shfl_xor(o0, off);
        o1 += __shfl_xor(o1, off);
    }
    if (lane == 0) {
        float py = tanhf(o0) * (2.f / 15.f) + ((0.5f + (float)oy) * (1.f / 15.f)) * 2.f - 1.f;
        float px = tanhf(o1) * (2.f / 15.f) + ((0.5f + (float)ox) * (1.f / 15.f)) * 2.f - 1.f;
        posb[bg * 512 + pos * 2 + 0] = py;
        posb[bg * 512 + pos * 2 + 1] = px;
    }
}

// ---------------- K3: bilinear KV sampling -> fp16 [b][s][c] directly ----------------
__global__ void sample_xs_kernel(const float* __restrict__ x, const float* __restrict__ posb,
                                 __half* __restrict__ xsh)
{
    const int cc = blockIdx.x, bg = blockIdx.y;
    const int b = bg / GG, g = bg - b * GG;
    const int s = threadIdx.x;
    float py = posb[bg * 512 + s * 2 + 0];
    float px = posb[bg * 512 + s * 2 + 1];
    float xi = (px + 1.f) * 0.5f * 31.f;
    float yi = (py + 1.f) * 0.5f * 31.f;
    float x0f = floorf(xi), y0f = floorf(yi);
    int x0 = (int)x0f, y0 = (int)y0f;
    float wx1 = xi - x0f, wy1 = yi - y0f;
    const float* img = x + ((size_t)(b * CC_ + g * NGC_ + cc)) * HWSZ;
    float acc = 0.f;
#pragma unroll
    for (int t = 0; t < 4; ++t) {
        int iy = y0 + (t >> 1), ix = x0 + (t & 1);
        float w = ((t >> 1) ? wy1 : 1.f - wy1) * ((t & 1) ? wx1 : 1.f - wx1);
        if (iy >= 0 && iy <= 31 && ix >= 0 && ix <= 31)
            acc = fmaf(img[iy * 32 + ix], w, acc);
    }
    xsh[((size_t)(b * NS_ + s)) * CC_ + g * NGC_ + cc] = __float2half(acc);
}

// ---------------- K5: full-MFMA attention with y-axis LDS table ----------------
__launch_bounds__(256)
__global__ void attn_mfma(const __half* __restrict__ qh, const __half* __restrict__ kt,
                          const __half* __restrict__ vt, const float* __restrict__ posb,
                          const float* __restrict__ rpe, __half* __restrict__ aoT)
{
    __shared__ __half rph[4096];
    __shared__ float4 ytab[512];
    const int bh = blockIdx.y;
    const int b = bh / NHD, h = bh - b * NHD;
    const int bg = b * GG + (h >> 1);
    const int tid = threadIdx.x;
    for (int e = tid; e < RPEW * RPEW; e += 256)
        rph[e] = __float2half(rpe[(size_t)h * (RPEW * RPEW) + e]);
    const int base_row = blockIdx.x * 2;
    for (int e = tid; e < 512; e += 256) {
        int rr = e >> 8, s = e & 255;
        float py = posb[bg * 512 + s * 2 + 0];
        float px = posb[bg * 512 + s * 2 + 1];
        float ycr = ((float)(base_row + rr) * (2.f / 31.f) - 1.f) * 15.5f + 31.f;
        float yi = fmaf(py, -15.5f, ycr);
        float y0f = floorf(yi);
        int iy = (int)y0f;
        float wy1 = yi - y0f, wy0 = 1.f - wy1;
        if ((unsigned)iy > 62u)       wy0 = 0.f;
        if ((unsigned)(iy + 1) > 62u) wy1 = 0.f;
        int ry0 = min(max(iy, 0), 62) * 63;
        int ry1 = min(max(iy + 1, 0), 62) * 63;
        float4 t;
        t.x = __int_as_float(ry0);
        t.y = __int_as_float(ry1);
        t.z = __uint_as_float(__builtin_bit_cast(unsigned, __floats2half2_rn(wy0, wy1)));
        t.w = px * 15.5f;
        ytab[rr * 256 + s] = t;
    }
    __syncthreads();

    const int wave = tid >> 6;
    const int lane = tid & 63;
    const int l15 = lane & 15, lhi = lane >> 4;
    const int qglob = blockIdx.x * 64 + wave * 16 + l15;
    const int col = qglob & 31;
    const float xc = ((float)col * (2.f / 31.f) - 1.f) * 15.5f + 31.f;
    const int rowl = wave >> 1;

    half8_t qf = *(const half8_t*)(qh + ((size_t)(b * HWSZ + qglob)) * CC_ + h * HCH + lhi * 8);

    const __half* kbase = kt + (size_t)bh * NS_ * 32;
    const __half* vbase = vt + (size_t)bh * 32 * NS_;

    f32x4_t oacc0 = {0.f,0.f,0.f,0.f}, oacc1 = {0.f,0.f,0.f,0.f};
    const f32x4_t zero4 = {0.f,0.f,0.f,0.f};
    float lsum = 0.f;

    for (int chunk = 0; chunk < 8; ++chunk) {
        const int sbase = chunk * 32;
        unsigned wa0 = 0, wa1 = 0, wb0 = 0, wb1 = 0;
#pragma unroll
        for (int t = 0; t < 2; ++t) {
            const int stile = sbase + t * 16;
            half8_t kf = *(const half8_t*)(kbase + (size_t)(stile + l15) * 32 + lhi * 8);
            f32x4_t sf = __builtin_amdgcn_mfma_f32_16x16x32_f16(kf, qf, zero4, 0, 0, 0);
            float pv[4];
#pragma unroll
            for (int r = 0; r < 4; ++r) {
                const int s = stile + lhi * 4 + r;
                float4 yt = ytab[rowl * 256 + s];
                int ry0 = __float_as_int(yt.x), ry1 = __float_as_int(yt.y);
                __half2 wyh = __builtin_bit_cast(__half2, __float_as_uint(yt.z));
                float wy0 = __low2float(wyh), wy1 = __high2float(wyh);
                float xi = xc - yt.w;
                float x0f = floorf(xi);
                int ix = (int)x0f;
                float wx1 = xi - x0f, wx0 = 1.f - wx1;
                if ((unsigned)ix > 62u)       wx0 = 0.f;
                if ((unsigned)(ix + 1) > 62u) wx1 = 0.f;
                int cx0 = min(max(ix, 0), 62);
                int cx1 = min(max(ix + 1, 0), 62);
                float t00 = __half2float(rph[ry0 + cx0]), t01 = __half2float(rph[ry0 + cx1]);
                float t10 = __half2float(rph[ry1 + cx0]), t11 = __half2float(rph[ry1 + cx1]);
                float bias = wy0 * fmaf(wx0, t00, wx1 * t01)
                           + wy1 * fmaf(wx0, t10, wx1 * t11);
                float p = __expf(sf[r] + bias);
                lsum += p;
                pv[r] = p;
            }
            unsigned w0 = __builtin_bit_cast(unsigned, __floats2half2_rn(pv[0], pv[1]));
            unsigned w1 = __builtin_bit_cast(unsigned, __floats2half2_rn(pv[2], pv[3]));
            if (t == 0) { wa0 = w0; wa1 = w1; } else { wb0 = w0; wb1 = w1; }
        }
        const int srcA = l15 + ((lhi & 1) << 5);
        const int srcB = srcA + 16;
        int g0a = __shfl((int)wa0, srcA), g0b = __shfl((int)wb0, srcA);
        int g1a = __shfl((int)wa1, srcA), g1b = __shfl((int)wb1, srcA);
        int g2a = __shfl((int)wa0, srcB), g2b = __shfl((int)wb0, srcB);
        int g3a = __shfl((int)wa1, srcB), g3b = __shfl((int)wb1, srcB);
        const bool hi = (lhi >= 2);
        u32x4_t bw;
        bw[0] = (unsigned)(hi ? g0b : g0a);
        bw[1] = (unsigned)(hi ? g1b : g1a);
        bw[2] = (unsigned)(hi ? g2b : g2a);
        bw[3] = (unsigned)(hi ? g3b : g3a);
        half8_t pf = __builtin_bit_cast(half8_t, bw);
        half8_t vf0 = *(const half8_t*)(vbase + (size_t)(l15) * NS_ + sbase + lhi * 8);
        half8_t vf1 = *(const half8_t*)(vbase + (size_t)(16 + l15) * NS_ + sbase + lhi * 8);
        oacc0 = __builtin_amdgcn_mfma_f32_16x16x32_f16(vf0, pf, oacc0, 0, 0, 0);
        oacc1 = __builtin_amdgcn_mfma_f32_16x16x32_f16(vf1, pf, oacc1, 0, 0, 0);
    }
    lsum += __shfl_xor(lsum, 16);
    lsum += __shfl_xor(lsum, 32);
    const float inv = 1.f / lsum;
    __half* og = aoT + ((size_t)(b * HWSZ + qglob)) * CC_ + h * HCH;
    {
        __half2 h0 = __floats2half2_rn(oacc0[0] * inv, oacc0[1] * inv);
        __half2 h1 = __floats2half2_rn(oacc0[2] * inv, oacc0[3] * inv);
        uint2 u;
        u.x = __builtin_bit_cast(unsigned, h0);
        u.y = __builtin_bit_cast(unsigned, h1);
        *(uint2*)(og + lhi * 4) = u;
        h0 = __floats2half2_rn(oacc1[0] * inv, oacc1[1] * inv);
        h1 = __floats2half2_rn(oacc1[2] * inv, oacc1[3] * inv);
        u.x = __builtin_bit_cast(unsigned, h0);
        u.y = __builtin_bit_cast(unsigned, h1);
        *(uint2*)(og + 16 + lhi * 4) = u;
    }
}

extern "C" void kernel_launch(void* const* d_in, const int* in_sizes, int n_in,
                              void* d_out, int out_size, void* d_ws, size_t ws_size,
                              hipStream_t stream) {
    (void)in_sizes; (void)n_in; (void)out_size; (void)ws_size;
    const float* x   = (const float*)d_in[0];
    const float* Wq  = (const float*)d_in[1];
    const float* bq  = (const float*)d_in[2];
    const float* Wk  = (const float*)d_in[3];
    const float* bk  = (const float*)d_in[4];
    const float* Wv  = (const float*)d_in[5];
    const float* bv  = (const float*)d_in[6];
    const float* Wo  = (const float*)d_in[7];
    const float* bo  = (const float*)d_in[8];
    const float* dww = (const float*)d_in[9];
    const float* dwb = (const float*)d_in[10];
    const float* lng = (const float*)d_in[11];
    const float* lnb = (const float*)d_in[12];
    const float* pww = (const float*)d_in[13];
    const float* rpe = (const float*)d_in[14];
    float* out = (float*)d_out;

    // Workspace (float slots); aliasing audited (R16/R17-validated layout):
    //  R (786432): xh (prep..conv_q) -> cobuf=R[0:393216] (dw..fin); rest unused
    //  qh == aoT alias (attn reads/writes same per-block region)
    float* p = (float*)d_ws;
    float* qbuf  = p; p += 1572864;                 // fp32 [b][c][n]
    float* posb  = p; p += 12288;
    __half* ktb  = (__half*)p; p += 196608;         // K fp16 [bh][s][32]
    __half* vth  = (__half*)p; p += 196608;         // V fp16 [bh][c][s]
    float* R     = p; p += 786432;
    __half* xh   = (__half*)R;
    float* cobuf = R;
    __half* qh   = (__half*)p; p += 786432;         // fp16 scaled [b][n][c]
    __half* aoT  = qh;
    __half* wqh  = (__half*)p; p += 73728;
    __half* woh  = (__half*)p; p += 73728;
    __half* wkh  = (__half*)p; p += 73728;
    __half* wvh  = (__half*)p; p += 73728;
    __half* xsh  = (__half*)p; p += 196608;         // fp16 [b][s][c]

    prep_kernel<<<dim3(960), 256, 0, stream>>>(Wq, Wo, Wk, Wv, wqh, woh, wkh, wvh, x, xh);
    convq_mfma<<<dim3(HWSZ / 32, CC_ / 64, BB), 256, 0, stream>>>(wqh, bq, xh, qbuf, qh);
    offset_dw_kernel<<<dim3(NGC_, 24), 256, 0, stream>>>(qbuf, dww, dwb, cobuf);
    offset_fin_kernel<<<dim3(1536), 256, 0, stream>>>(cobuf, lng, lnb, pww, posb);
    sample_xs_kernel<<<dim3(NGC_, 24), 256, 0, stream>>>(x, posb, xsh);
    convkv_mfma<CC_><<<dim3(NS_ / 32, CC_ / 64, BB), 256, 0, stream>>>(wkh, bk, wvh, bv, xsh, ktb, vth);
    attn_mfma<<<dim3(16, BB * NHD), 256, 0, stream>>>(qh, ktb, vth, posb, rpe, aoT);
    conv1x1_mfma_h<CC_><<<dim3(HWSZ / 32, CC_ / 64, BB), 256, 0, stream>>>(woh, bo, aoT, out, HWSZ, CC_);
}

// Round 20
// 83.845 us; speedup vs baseline: 1.6230x; 1.0016x over previous
//
#include <hip/hip_runtime.h>
#include <hip/hip_bf16.h>
#include <hip/hip_fp16.h>

#define BB 4
#define CC_ 384
#define HH 32
#define WW 32
#define HWSZ 1024
#define NHD 12
#define HCH 32
#define GG 6
#define NGC_ 64
#define GHD 2
#define HK_ 16
#define WK_ 16
#define NS_ 256
#define RPEW 63
#define SCALE_ 0.17677669529663687f

typedef _Float16 half8_t __attribute__((ext_vector_type(8)));
typedef float f32x4_t __attribute__((ext_vector_type(4)));
typedef unsigned u32x4_t __attribute__((ext_vector_type(4)));

// ---------------- prep: 4x weight cvt + x transpose in ONE launch ----------------
__global__ __launch_bounds__(256)
void prep_kernel(const float* __restrict__ w0, const float* __restrict__ w1,
                 const float* __restrict__ w2, const float* __restrict__ w3,
                 __half* __restrict__ o0, __half* __restrict__ o1,
                 __half* __restrict__ o2, __half* __restrict__ o3,
                 const float* __restrict__ X, __half* __restrict__ XT)
{
    __shared__ float tile[64][65];
    const int bid = blockIdx.x;
    const int tid = threadIdx.x;
    if (bid < 576) {
        const int m = bid / 144;
        const float* src = (m == 0) ? w0 : (m == 1) ? w1 : (m == 2) ? w2 : w3;
        __half* dst = (m == 0) ? o0 : (m == 1) ? o1 : (m == 2) ? o2 : o3;
        int i = (bid - m * 144) * 256 + tid;
        if (i < CC_ * CC_ / 4) {
            float4 v = *(const float4*)(src + (size_t)i * 4);
            __half2* d = (__half2*)(dst + (size_t)i * 4);
            d[0] = __floats2half2_rn(v.x, v.y);
            d[1] = __floats2half2_rn(v.z, v.w);
        }
    } else {
        const int t = bid - 576;
        const int n0 = (t & 15) * 64;
        const int c0 = ((t >> 4) % 6) * 64;
        const int b = t / 96;
        const int tn = tid & 63, tg = tid >> 6;
#pragma unroll
        for (int k = 0; k < 16; ++k) {
            int r = k * 4 + tg;
            tile[r][tn] = X[((size_t)(b * CC_ + c0 + r)) * HWSZ + n0 + tn];
        }
        __syncthreads();
        const int cp = tg * 16;
        __half hb[16] __attribute__((aligned(16)));
#pragma unroll
        for (int j = 0; j < 16; ++j) hb[j] = __float2half(tile[cp + j][tn]);
        __half* dst = XT + ((size_t)(b * HWSZ + n0 + tn)) * CC_ + c0 + cp;
        *(uint4*)(dst) = *(uint4*)(hb);
        *(uint4*)(dst + 8) = *(uint4*)(hb + 8);
    }
}

// ---------------- K6: MFMA fp16 conv1x1 (fp32 out) ----------------
template<int CIN>
__global__ __launch_bounds__(256)
void conv1x1_mfma_h(const __half* __restrict__ Wh, const float* __restrict__ bias,
                    const __half* __restrict__ XT, float* __restrict__ Y, int N, int OC)
{
    const int tid = threadIdx.x;
    const int wv = tid >> 6;
    const int lane = tid & 63;
    const int l15 = lane & 15, lhi = lane >> 4;
    const int otile = blockIdx.y * 64 + wv * 16;
    const int ntile = blockIdx.x * 32;
    const int b = blockIdx.z;

    const __half* Wp = Wh + (size_t)(otile + l15) * CIN + lhi * 8;
    const __half* Xp0 = XT + ((size_t)(b * N + ntile + l15)) * CIN + lhi * 8;
    const __half* Xp1 = Xp0 + (size_t)16 * CIN;

    f32x4_t acc0 = {0.f, 0.f, 0.f, 0.f}, acc1 = {0.f, 0.f, 0.f, 0.f};
#pragma unroll
    for (int k0 = 0; k0 < CIN; k0 += 32) {
        half8_t af = *(const half8_t*)(Wp + k0);
        half8_t b0 = *(const half8_t*)(Xp0 + k0);
        half8_t b1 = *(const half8_t*)(Xp1 + k0);
        acc0 = __builtin_amdgcn_mfma_f32_16x16x32_f16(af, b0, acc0, 0, 0, 0);
        acc1 = __builtin_amdgcn_mfma_f32_16x16x32_f16(af, b1, acc1, 0, 0, 0);
    }
#pragma unroll
    for (int r = 0; r < 4; ++r) {
        float bv = bias[otile + lhi * 4 + r];
        float* yr = Y + ((size_t)(b * OC + otile + lhi * 4 + r)) * N + ntile + l15;
        yr[0]  = acc0[r] + bv;
        yr[16] = acc1[r] + bv;
    }
}

// ---------------- K1: MFMA conv for q: fp32 [b][c][n] + fp16 SCALED [b][n][c] ----------------
__global__ __launch_bounds__(256)
void convq_mfma(const __half* __restrict__ Wh, const float* __restrict__ bias,
                const __half* __restrict__ XT, float* __restrict__ Y,
                __half* __restrict__ Qh)
{
    const int tid = threadIdx.x;
    const int wv = tid >> 6;
    const int lane = tid & 63;
    const int l15 = lane & 15, lhi = lane >> 4;
    const int otile = blockIdx.y * 64 + wv * 16;
    const int ntile = blockIdx.x * 32;
    const int b = blockIdx.z;

    const __half* Wp = Wh + (size_t)(otile + l15) * CC_ + lhi * 8;
    const __half* Xp0 = XT + ((size_t)(b * HWSZ + ntile + l15)) * CC_ + lhi * 8;
    const __half* Xp1 = Xp0 + (size_t)16 * CC_;

    f32x4_t acc0 = {0.f, 0.f, 0.f, 0.f}, acc1 = {0.f, 0.f, 0.f, 0.f};
#pragma unroll
    for (int k0 = 0; k0 < CC_; k0 += 32) {
        half8_t af = *(const half8_t*)(Wp + k0);
        half8_t b0 = *(const half8_t*)(Xp0 + k0);
        half8_t b1 = *(const half8_t*)(Xp1 + k0);
        acc0 = __builtin_amdgcn_mfma_f32_16x16x32_f16(af, b0, acc0, 0, 0, 0);
        acc1 = __builtin_amdgcn_mfma_f32_16x16x32_f16(af, b1, acc1, 0, 0, 0);
    }
    float bv[4];
#pragma unroll
    for (int r = 0; r < 4; ++r) bv[r] = bias[otile + lhi * 4 + r];
#pragma unroll
    for (int r = 0; r < 4; ++r) {
        float* yr = Y + ((size_t)(b * CC_ + otile + lhi * 4 + r)) * HWSZ + ntile + l15;
        yr[0]  = acc0[r] + bv[r];
        yr[16] = acc1[r] + bv[r];
    }
    {
        int n0 = ntile + l15;
        __half2 h0 = __floats2half2_rn((acc0[0] + bv[0]) * SCALE_, (acc0[1] + bv[1]) * SCALE_);
        __half2 h1 = __floats2half2_rn((acc0[2] + bv[2]) * SCALE_, (acc0[3] + bv[3]) * SCALE_);
        uint2 u;
        u.x = __builtin_bit_cast(unsigned, h0);
        u.y = __builtin_bit_cast(unsigned, h1);
        *(uint2*)(Qh + ((size_t)(b * HWSZ + n0)) * CC_ + otile + lhi * 4) = u;
        h0 = __floats2half2_rn((acc1[0] + bv[0]) * SCALE_, (acc1[1] + bv[1]) * SCALE_);
        h1 = __floats2half2_rn((acc1[2] + bv[2]) * SCALE_, (acc1[3] + bv[3]) * SCALE_);
        u.x = __builtin_bit_cast(unsigned, h0);
        u.y = __builtin_bit_cast(unsigned, h1);
        *(uint2*)(Qh + ((size_t)(b * HWSZ + n0 + 16)) * CC_ + otile + lhi * 4) = u;
    }
}

// ---------------- K4: MFMA fused K+V conv; K fp16 [bh][s][32], V fp16 [bh][c][s] ----------------
template<int CIN>
__global__ __launch_bounds__(256)
void convkv_mfma(const __half* __restrict__ Wkh, const float* __restrict__ bk,
                 const __half* __restrict__ Wvh, const float* __restrict__ bv,
                 const __half* __restrict__ XS, __half* __restrict__ Yk,
                 __half* __restrict__ Yv)
{
    const int tid = threadIdx.x;
    const int wv = tid >> 6;
    const int lane = tid & 63;
    const int l15 = lane & 15, lhi = lane >> 4;
    const int otile = blockIdx.y * 64 + wv * 16;
    const int stile = blockIdx.x * 32;
    const int b = blockIdx.z;

    const __half* Wkp = Wkh + (size_t)(otile + l15) * CIN + lhi * 8;
    const __half* Wvp = Wvh + (size_t)(otile + l15) * CIN + lhi * 8;
    const __half* Xp0 = XS + ((size_t)(b * NS_ + stile + l15)) * CIN + lhi * 8;
    const __half* Xp1 = Xp0 + (size_t)16 * CIN;

    f32x4_t ka0 = {0.f,0.f,0.f,0.f}, ka1 = {0.f,0.f,0.f,0.f};
    f32x4_t va0 = {0.f,0.f,0.f,0.f}, va1 = {0.f,0.f,0.f,0.f};
#pragma unroll
    for (int c0 = 0; c0 < CIN; c0 += 32) {
        half8_t ak = *(const half8_t*)(Wkp + c0);
        half8_t av = *(const half8_t*)(Wvp + c0);
        half8_t b0 = *(const half8_t*)(Xp0 + c0);
        half8_t b1 = *(const half8_t*)(Xp1 + c0);
        ka0 = __builtin_amdgcn_mfma_f32_16x16x32_f16(ak, b0, ka0, 0, 0, 0);
        ka1 = __builtin_amdgcn_mfma_f32_16x16x32_f16(ak, b1, ka1, 0, 0, 0);
        va0 = __builtin_amdgcn_mfma_f32_16x16x32_f16(av, b0, va0, 0, 0, 0);
        va1 = __builtin_amdgcn_mfma_f32_16x16x32_f16(av, b1, va1, 0, 0, 0);
    }
    const int h = otile >> 5;
    const int c32 = (otile & 31) + lhi * 4;
    const size_t bh = (size_t)(b * NHD + h);
    float bkv[4], bvv[4];
#pragma unroll
    for (int r = 0; r < 4; ++r) {
        bkv[r] = bk[otile + lhi * 4 + r];
        bvv[r] = bv[otile + lhi * 4 + r];
    }
    {
        size_t base = (bh * NS_ + stile + l15) * 32 + c32;
        __half2 kh[2];
        kh[0] = __floats2half2_rn(ka0[0] + bkv[0], ka0[1] + bkv[1]);
        kh[1] = __floats2half2_rn(ka0[2] + bkv[2], ka0[3] + bkv[3]);
        *(uint2*)(Yk + base) = *(uint2*)kh;
        base = (bh * NS_ + stile + 16 + l15) * 32 + c32;
        kh[0] = __floats2half2_rn(ka1[0] + bkv[0], ka1[1] + bkv[1]);
        kh[1] = __floats2half2_rn(ka1[2] + bkv[2], ka1[3] + bkv[3]);
        *(uint2*)(Yk + base) = *(uint2*)kh;
    }
    {
        __half* vdst = Yv + (bh * 32 + c32) * NS_;
#pragma unroll
        for (int r = 0; r < 4; ++r) {
            vdst[(size_t)r * NS_ + stile + l15]      = __float2half(va0[r] + bvv[r]);
            vdst[(size_t)r * NS_ + stile + 16 + l15] = __float2half(va1[r] + bvv[r]);
        }
    }
}

// ---------------- K2a: depthwise conv 5x5 stride 2, transposed output [bg][pos][ch] ----------------
__global__ void offset_dw_kernel(const float* __restrict__ qb, const float* __restrict__ dww,
                                 const float* __restrict__ dwb, float* __restrict__ cobuf)
{
    __shared__ float img[HWSZ];
    const int c = blockIdx.x, bg = blockIdx.y;
    const int b = bg / GG, g = bg - b * GG;
    const int tid = threadIdx.x;
    const float* src = qb + ((size_t)(b * CC_ + g * NGC_ + c)) * HWSZ;
#pragma unroll
    for (int e = tid; e < HWSZ; e += 256) img[e] = src[e];
    __syncthreads();
    const int oy = tid >> 4, ox = tid & 15;
    float s = dwb[c];
    const float* wf = dww + c * 25;
    const int iy0 = oy * 2 - 2, ix0 = ox * 2 - 2;
#pragma unroll
    for (int ky = 0; ky < 5; ++ky) {
        int iy = iy0 + ky;
        if (iy < 0 || iy > 31) continue;
#pragma unroll
        for (int kx = 0; kx < 5; ++kx) {
            int ix = ix0 + kx;
            if (ix < 0 || ix > 31) continue;
            s = fmaf(img[iy * 32 + ix], wf[ky * 5 + kx], s);
        }
    }
    cobuf[((size_t)(bg * 256 + tid)) * NGC_ + c] = s;
}

// ---------------- K2b+K3 fused: LN+GELU+pw+tanh -> pos, then bilinear sample -> xsh ----------------
// grid: 1536 blocks x 256 thr = 4 waves; wave = 1 position (lane = channel).
// Phase 2: thread (wv, lane) samples x[b][g*64+lane] at pos of block-position wv.
__global__ void offset_finsample_kernel(const float* __restrict__ cobuf, const float* __restrict__ lng,
                                        const float* __restrict__ lnb, const float* __restrict__ pww,
                                        const float* __restrict__ x, float* __restrict__ posb,
                                        __half* __restrict__ xsh)
{
    __shared__ float pos_s[8];     // 4 positions x (py, px)
    const int lane = threadIdx.x & 63;
    const int wv = threadIdx.x >> 6;
    const int gpos = blockIdx.x * 4 + wv;          // 0..6143, block-aligned within bg
    const int bg = gpos >> 8, pos = gpos & 255;
    const int oy = (pos >> 4), ox = pos & 15;
    const int b = bg / GG, g = bg - b * GG;

    float v = cobuf[(size_t)gpos * NGC_ + lane];
    float s1 = v, s2 = v * v;
#pragma unroll
    for (int off = 32; off >= 1; off >>= 1) {
        s1 += __shfl_xor(s1, off);
        s2 += __shfl_xor(s2, off);
    }
    float mu = s1 * (1.f / 64.f);
    float var = s2 * (1.f / 64.f) - mu * mu;
    float rstd = rsqrtf(var + 1e-5f);
    float t = (v - mu) * rstd * lng[lane] + lnb[lane];
    float gv = 0.5f * t * (1.f + erff(t * 0.70710678118654752f));
    float o0 = pww[lane] * gv;
    float o1 = pww[64 + lane] * gv;
#pragma unroll
    for (int off = 32; off >= 1; off >>= 1) {
        o0 += __shfl_xor(o0, off);
        o1 += __shfl_xor(o1, off);
    }
    if (lane == 0) {
        float py = tanhf(o0) * (2.f / 15.f) + ((0.5f + (float)oy) * (1.f / 15.f)) * 2.f - 1.f;
        float px = tanhf(o1) * (2.f / 15.f) + ((0.5f + (float)ox) * (1.f / 15.f)) * 2.f - 1.f;
        posb[bg * 512 + pos * 2 + 0] = py;
        posb[bg * 512 + pos * 2 + 1] = px;
        pos_s[wv * 2 + 0] = py;
        pos_s[wv * 2 + 1] = px;
    }
    __syncthreads();

    // one bilinear tap set per thread: sample channel (g*64+lane) at this wave's pos
    float py = pos_s[wv * 2 + 0], px = pos_s[wv * 2 + 1];
    float xi = (px + 1.f) * 0.5f * 31.f;
    float yi = (py + 1.f) * 0.5f * 31.f;
    float x0f = floorf(xi), y0f = floorf(yi);
    int x0 = (int)x0f, y0 = (int)y0f;
    float wx1 = xi - x0f, wy1 = yi - y0f;
    const float* img = x + ((size_t)(b * CC_ + g * NGC_ + lane)) * HWSZ;
    float acc = 0.f;
#pragma unroll
    for (int tt = 0; tt < 4; ++tt) {
        int iy = y0 + (tt >> 1), ix = x0 + (tt & 1);
        float w = ((tt >> 1) ? wy1 : 1.f - wy1) * ((tt & 1) ? wx1 : 1.f - wx1);
        if (iy >= 0 && iy <= 31 && ix >= 0 && ix <= 31)
            acc = fmaf(img[iy * 32 + ix], w, acc);
    }
    xsh[((size_t)(b * NS_ + pos)) * CC_ + g * NGC_ + lane] = __float2half(acc);
}

// ---------------- K5: full-MFMA attention with y-axis LDS table ----------------
__launch_bounds__(256)
__global__ void attn_mfma(const __half* __restrict__ qh, const __half* __restrict__ kt,
                          const __half* __restrict__ vt, const float* __restrict__ posb,
                          const float* __restrict__ rpe, __half* __restrict__ aoT)
{
    __shared__ __half rph[4096];
    __shared__ float4 ytab[512];
    const int bh = blockIdx.y;
    const int b = bh / NHD, h = bh - b * NHD;
    const int bg = b * GG + (h >> 1);
    const int tid = threadIdx.x;
    for (int e = tid; e < RPEW * RPEW; e += 256)
        rph[e] = __float2half(rpe[(size_t)h * (RPEW * RPEW) + e]);
    const int base_row = blockIdx.x * 2;
    for (int e = tid; e < 512; e += 256) {
        int rr = e >> 8, s = e & 255;
        float py = posb[bg * 512 + s * 2 + 0];
        float px = posb[bg * 512 + s * 2 + 1];
        float ycr = ((float)(base_row + rr) * (2.f / 31.f) - 1.f) * 15.5f + 31.f;
        float yi = fmaf(py, -15.5f, ycr);
        float y0f = floorf(yi);
        int iy = (int)y0f;
        float wy1 = yi - y0f, wy0 = 1.f - wy1;
        if ((unsigned)iy > 62u)       wy0 = 0.f;
        if ((unsigned)(iy + 1) > 62u) wy1 = 0.f;
        int ry0 = min(max(iy, 0), 62) * 63;
        int ry1 = min(max(iy + 1, 0), 62) * 63;
        float4 t;
        t.x = __int_as_float(ry0);
        t.y = __int_as_float(ry1);
        t.z = __uint_as_float(__builtin_bit_cast(unsigned, __floats2half2_rn(wy0, wy1)));
        t.w = px * 15.5f;
        ytab[rr * 256 + s] = t;
    }
    __syncthreads();

    const int wave = tid >> 6;
    const int lane = tid & 63;
    const int l15 = lane & 15, lhi = lane >> 4;
    const int qglob = blockIdx.x * 64 + wave * 16 + l15;
    const int col = qglob & 31;
    const float xc = ((float)col * (2.f / 31.f) - 1.f) * 15.5f + 31.f;
    const int rowl = wave >> 1;

    half8_t qf = *(const half8_t*)(qh + ((size_t)(b * HWSZ + qglob)) * CC_ + h * HCH + lhi * 8);

    const __half* kbase = kt + (size_t)bh * NS_ * 32;
    const __half* vbase = vt + (size_t)bh * 32 * NS_;

    f32x4_t oacc0 = {0.f,0.f,0.f,0.f}, oacc1 = {0.f,0.f,0.f,0.f};
    const f32x4_t zero4 = {0.f,0.f,0.f,0.f};
    float lsum = 0.f;

    for (int chunk = 0; chunk < 8; ++chunk) {
        const int sbase = chunk * 32;
        unsigned wa0 = 0, wa1 = 0, wb0 = 0, wb1 = 0;
#pragma unroll
        for (int t = 0; t < 2; ++t) {
            const int stile = sbase + t * 16;
            half8_t kf = *(const half8_t*)(kbase + (size_t)(stile + l15) * 32 + lhi * 8);
            f32x4_t sf = __builtin_amdgcn_mfma_f32_16x16x32_f16(kf, qf, zero4, 0, 0, 0);
            float pv[4];
#pragma unroll
            for (int r = 0; r < 4; ++r) {
                const int s = stile + lhi * 4 + r;
                float4 yt = ytab[rowl * 256 + s];
                int ry0 = __float_as_int(yt.x), ry1 = __float_as_int(yt.y);
                __half2 wyh = __builtin_bit_cast(__half2, __float_as_uint(yt.z));
                float wy0 = __low2float(wyh), wy1 = __high2float(wyh);
                float xi = xc - yt.w;
                float x0f = floorf(xi);
                int ix = (int)x0f;
                float wx1 = xi - x0f, wx0 = 1.f - wx1;
                if ((unsigned)ix > 62u)       wx0 = 0.f;
                if ((unsigned)(ix + 1) > 62u) wx1 = 0.f;
                int cx0 = min(max(ix, 0), 62);
                int cx1 = min(max(ix + 1, 0), 62);
                float t00 = __half2float(rph[ry0 + cx0]), t01 = __half2float(rph[ry0 + cx1]);
                float t10 = __half2float(rph[ry1 + cx0]), t11 = __half2float(rph[ry1 + cx1]);
                float bias = wy0 * fmaf(wx0, t00, wx1 * t01)
                           + wy1 * fmaf(wx0, t10, wx1 * t11);
                float p = __expf(sf[r] + bias);
                lsum += p;
                pv[r] = p;
            }
            unsigned w0 = __builtin_bit_cast(unsigned, __floats2half2_rn(pv[0], pv[1]));
            unsigned w1 = __builtin_bit_cast(unsigned, __floats2half2_rn(pv[2], pv[3]));
            if (t == 0) { wa0 = w0; wa1 = w1; } else { wb0 = w0; wb1 = w1; }
        }
        const int srcA = l15 + ((lhi & 1) << 5);
        const int srcB = srcA + 16;
        int g0a = __shfl((int)wa0, srcA), g0b = __shfl((int)wb0, srcA);
        int g1a = __shfl((int)wa1, srcA), g1b = __shfl((int)wb1, srcA);
        int g2a = __shfl((int)wa0, srcB), g2b = __shfl((int)wb0, srcB);
        int g3a = __shfl((int)wa1, srcB), g3b = __shfl((int)wb1, srcB);
        const bool hi = (lhi >= 2);
        u32x4_t bw;
        bw[0] = (unsigned)(hi ? g0b : g0a);
        bw[1] = (unsigned)(hi ? g1b : g1a);
        bw[2] = (unsigned)(hi ? g2b : g2a);
        bw[3] = (unsigned)(hi ? g3b : g3a);
        half8_t pf = __builtin_bit_cast(half8_t, bw);
        half8_t vf0 = *(const half8_t*)(vbase + (size_t)(l15) * NS_ + sbase + lhi * 8);
        half8_t vf1 = *(const half8_t*)(vbase + (size_t)(16 + l15) * NS_ + sbase + lhi * 8);
        oacc0 = __builtin_amdgcn_mfma_f32_16x16x32_f16(vf0, pf, oacc0, 0, 0, 0);
        oacc1 = __builtin_amdgcn_mfma_f32_16x16x32_f16(vf1, pf, oacc1, 0, 0, 0);
    }
    lsum += __shfl_xor(lsum, 16);
    lsum += __shfl_xor(lsum, 32);
    const float inv = 1.f / lsum;
    __half* og = aoT + ((size_t)(b * HWSZ + qglob)) * CC_ + h * HCH;
    {
        __half2 h0 = __floats2half2_rn(oacc0[0] * inv, oacc0[1] * inv);
        __half2 h1 = __floats2half2_rn(oacc0[2] * inv, oacc0[3] * inv);
        uint2 u;
        u.x = __builtin_bit_cast(unsigned, h0);
        u.y = __builtin_bit_cast(unsigned, h1);
        *(uint2*)(og + lhi * 4) = u;
        h0 = __floats2half2_rn(oacc1[0] * inv, oacc1[1] * inv);
        h1 = __floats2half2_rn(oacc1[2] * inv, oacc1[3] * inv);
        u.x = __builtin_bit_cast(unsigned, h0);
        u.y = __builtin_bit_cast(unsigned, h1);
        *(uint2*)(og + 16 + lhi * 4) = u;
    }
}

extern "C" void kernel_launch(void* const* d_in, const int* in_sizes, int n_in,
                              void* d_out, int out_size, void* d_ws, size_t ws_size,
                              hipStream_t stream) {
    (void)in_sizes; (void)n_in; (void)out_size; (void)ws_size;
    const float* x   = (const float*)d_in[0];
    const float* Wq  = (const float*)d_in[1];
    const float* bq  = (const float*)d_in[2];
    const float* Wk  = (const float*)d_in[3];
    const float* bk  = (const float*)d_in[4];
    const float* Wv  = (const float*)d_in[5];
    const float* bv  = (const float*)d_in[6];
    const float* Wo  = (const float*)d_in[7];
    const float* bo  = (const float*)d_in[8];
    const float* dww = (const float*)d_in[9];
    const float* dwb = (const float*)d_in[10];
    const float* lng = (const float*)d_in[11];
    const float* lnb = (const float*)d_in[12];
    const float* pww = (const float*)d_in[13];
    const float* rpe = (const float*)d_in[14];
    float* out = (float*)d_out;

    // Workspace (float slots); aliasing audited (R16-R18-validated layout):
    //  R (786432): xh (prep..conv_q) -> cobuf=R[0:393216] (dw..finsample)
    //  qh == aoT alias (attn reads/writes same per-block region)
    float* p = (float*)d_ws;
    float* qbuf  = p; p += 1572864;                 // fp32 [b][c][n]
    float* posb  = p; p += 12288;
    __half* ktb  = (__half*)p; p += 196608;         // K fp16 [bh][s][32]
    __half* vth  = (__half*)p; p += 196608;         // V fp16 [bh][c][s]
    float* R     = p; p += 786432;
    __half* xh   = (__half*)R;
    float* cobuf = R;
    __half* qh   = (__half*)p; p += 786432;         // fp16 scaled [b][n][c]
    __half* aoT  = qh;
    __half* wqh  = (__half*)p; p += 73728;
    __half* woh  = (__half*)p; p += 73728;
    __half* wkh  = (__half*)p; p += 73728;
    __half* wvh  = (__half*)p; p += 73728;
    __half* xsh  = (__half*)p; p += 196608;         // fp16 [b][s][c]

    prep_kernel<<<dim3(960), 256, 0, stream>>>(Wq, Wo, Wk, Wv, wqh, woh, wkh, wvh, x, xh);
    convq_mfma<<<dim3(HWSZ / 32, CC_ / 64, BB), 256, 0, stream>>>(wqh, bq, xh, qbuf, qh);
    offset_dw_kernel<<<dim3(NGC_, 24), 256, 0, stream>>>(qbuf, dww, dwb, cobuf);
    offset_finsample_kernel<<<dim3(1536), 256, 0, stream>>>(cobuf, lng, lnb, pww, x, posb, xsh);
    convkv_mfma<CC_><<<dim3(NS_ / 32, CC_ / 64, BB), 256, 0, stream>>>(wkh, bk, wvh, bv, xsh, ktb, vth);
    attn_mfma<<<dim3(16, BB * NHD), 256, 0, stream>>>(qh, ktb, vth, posb, rpe, aoT);
    conv1x1_mfma_h<CC_><<<dim3(HWSZ / 32, CC_ / 64, BB), 256, 0, stream>>>(woh, bo, aoT, out, HWSZ, CC_);
}

// Round 21
// 83.742 us; speedup vs baseline: 1.6250x; 1.0012x over previous
//
#include <hip/hip_runtime.h>
#include <hip/hip_bf16.h>
#include <hip/hip_fp16.h>

#define BB 4
#define CC_ 384
#define HH 32
#define WW 32
#define HWSZ 1024
#define NHD 12
#define HCH 32
#define GG 6
#define NGC_ 64
#define GHD 2
#define HK_ 16
#define WK_ 16
#define NS_ 256
#define RPEW 63
#define SCALE_ 0.17677669529663687f

typedef _Float16 half8_t __attribute__((ext_vector_type(8)));
typedef float f32x4_t __attribute__((ext_vector_type(4)));
typedef unsigned u32x4_t __attribute__((ext_vector_type(4)));

// ---------------- prep: 4x weight cvt + x transpose in ONE launch ----------------
__global__ __launch_bounds__(256)
void prep_kernel(const float* __restrict__ w0, const float* __restrict__ w1,
                 const float* __restrict__ w2, const float* __restrict__ w3,
                 __half* __restrict__ o0, __half* __restrict__ o1,
                 __half* __restrict__ o2, __half* __restrict__ o3,
                 const float* __restrict__ X, __half* __restrict__ XT)
{
    __shared__ float tile[64][65];
    const int bid = blockIdx.x;
    const int tid = threadIdx.x;
    if (bid < 576) {
        const int m = bid / 144;
        const float* src = (m == 0) ? w0 : (m == 1) ? w1 : (m == 2) ? w2 : w3;
        __half* dst = (m == 0) ? o0 : (m == 1) ? o1 : (m == 2) ? o2 : o3;
        int i = (bid - m * 144) * 256 + tid;
        if (i < CC_ * CC_ / 4) {
            float4 v = *(const float4*)(src + (size_t)i * 4);
            __half2* d = (__half2*)(dst + (size_t)i * 4);
            d[0] = __floats2half2_rn(v.x, v.y);
            d[1] = __floats2half2_rn(v.z, v.w);
        }
    } else {
        const int t = bid - 576;
        const int n0 = (t & 15) * 64;
        const int c0 = ((t >> 4) % 6) * 64;
        const int b = t / 96;
        const int tn = tid & 63, tg = tid >> 6;
#pragma unroll
        for (int k = 0; k < 16; ++k) {
            int r = k * 4 + tg;
            tile[r][tn] = X[((size_t)(b * CC_ + c0 + r)) * HWSZ + n0 + tn];
        }
        __syncthreads();
        const int cp = tg * 16;
        __half hb[16] __attribute__((aligned(16)));
#pragma unroll
        for (int j = 0; j < 16; ++j) hb[j] = __float2half(tile[cp + j][tn]);
        __half* dst = XT + ((size_t)(b * HWSZ + n0 + tn)) * CC_ + c0 + cp;
        *(uint4*)(dst) = *(uint4*)(hb);
        *(uint4*)(dst + 8) = *(uint4*)(hb + 8);
    }
}

// ---------------- K6: MFMA fp16 conv1x1 (fp32 out) ----------------
template<int CIN>
__global__ __launch_bounds__(256)
void conv1x1_mfma_h(const __half* __restrict__ Wh, const float* __restrict__ bias,
                    const __half* __restrict__ XT, float* __restrict__ Y, int N, int OC)
{
    const int tid = threadIdx.x;
    const int wv = tid >> 6;
    const int lane = tid & 63;
    const int l15 = lane & 15, lhi = lane >> 4;
    const int otile = blockIdx.y * 64 + wv * 16;
    const int ntile = blockIdx.x * 32;
    const int b = blockIdx.z;

    const __half* Wp = Wh + (size_t)(otile + l15) * CIN + lhi * 8;
    const __half* Xp0 = XT + ((size_t)(b * N + ntile + l15)) * CIN + lhi * 8;
    const __half* Xp1 = Xp0 + (size_t)16 * CIN;

    f32x4_t acc0 = {0.f, 0.f, 0.f, 0.f}, acc1 = {0.f, 0.f, 0.f, 0.f};
#pragma unroll
    for (int k0 = 0; k0 < CIN; k0 += 32) {
        half8_t af = *(const half8_t*)(Wp + k0);
        half8_t b0 = *(const half8_t*)(Xp0 + k0);
        half8_t b1 = *(const half8_t*)(Xp1 + k0);
        acc0 = __builtin_amdgcn_mfma_f32_16x16x32_f16(af, b0, acc0, 0, 0, 0);
        acc1 = __builtin_amdgcn_mfma_f32_16x16x32_f16(af, b1, acc1, 0, 0, 0);
    }
#pragma unroll
    for (int r = 0; r < 4; ++r) {
        float bv = bias[otile + lhi * 4 + r];
        float* yr = Y + ((size_t)(b * OC + otile + lhi * 4 + r)) * N + ntile + l15;
        yr[0]  = acc0[r] + bv;
        yr[16] = acc1[r] + bv;
    }
}

// ---------------- K1: MFMA conv for q: fp32 [b][c][n] + fp16 SCALED [b][n][c] ----------------
__global__ __launch_bounds__(256)
void convq_mfma(const __half* __restrict__ Wh, const float* __restrict__ bias,
                const __half* __restrict__ XT, float* __restrict__ Y,
                __half* __restrict__ Qh)
{
    const int tid = threadIdx.x;
    const int wv = tid >> 6;
    const int lane = tid & 63;
    const int l15 = lane & 15, lhi = lane >> 4;
    const int otile = blockIdx.y * 64 + wv * 16;
    const int ntile = blockIdx.x * 32;
    const int b = blockIdx.z;

    const __half* Wp = Wh + (size_t)(otile + l15) * CC_ + lhi * 8;
    const __half* Xp0 = XT + ((size_t)(b * HWSZ + ntile + l15)) * CC_ + lhi * 8;
    const __half* Xp1 = Xp0 + (size_t)16 * CC_;

    f32x4_t acc0 = {0.f, 0.f, 0.f, 0.f}, acc1 = {0.f, 0.f, 0.f, 0.f};
#pragma unroll
    for (int k0 = 0; k0 < CC_; k0 += 32) {
        half8_t af = *(const half8_t*)(Wp + k0);
        half8_t b0 = *(const half8_t*)(Xp0 + k0);
        half8_t b1 = *(const half8_t*)(Xp1 + k0);
        acc0 = __builtin_amdgcn_mfma_f32_16x16x32_f16(af, b0, acc0, 0, 0, 0);
        acc1 = __builtin_amdgcn_mfma_f32_16x16x32_f16(af, b1, acc1, 0, 0, 0);
    }
    float bv[4];
#pragma unroll
    for (int r = 0; r < 4; ++r) bv[r] = bias[otile + lhi * 4 + r];
#pragma unroll
    for (int r = 0; r < 4; ++r) {
        float* yr = Y + ((size_t)(b * CC_ + otile + lhi * 4 + r)) * HWSZ + ntile + l15;
        yr[0]  = acc0[r] + bv[r];
        yr[16] = acc1[r] + bv[r];
    }
    {
        int n0 = ntile + l15;
        __half2 h0 = __floats2half2_rn((acc0[0] + bv[0]) * SCALE_, (acc0[1] + bv[1]) * SCALE_);
        __half2 h1 = __floats2half2_rn((acc0[2] + bv[2]) * SCALE_, (acc0[3] + bv[3]) * SCALE_);
        uint2 u;
        u.x = __builtin_bit_cast(unsigned, h0);
        u.y = __builtin_bit_cast(unsigned, h1);
        *(uint2*)(Qh + ((size_t)(b * HWSZ + n0)) * CC_ + otile + lhi * 4) = u;
        h0 = __floats2half2_rn((acc1[0] + bv[0]) * SCALE_, (acc1[1] + bv[1]) * SCALE_);
        h1 = __floats2half2_rn((acc1[2] + bv[2]) * SCALE_, (acc1[3] + bv[3]) * SCALE_);
        u.x = __builtin_bit_cast(unsigned, h0);
        u.y = __builtin_bit_cast(unsigned, h1);
        *(uint2*)(Qh + ((size_t)(b * HWSZ + n0 + 16)) * CC_ + otile + lhi * 4) = u;
    }
}

// ---------------- K4: MFMA fused K+V conv; K fp16 [bh][s][32], V fp16 [bh][c][s] ----------------
template<int CIN>
__global__ __launch_bounds__(256)
void convkv_mfma(const __half* __restrict__ Wkh, const float* __restrict__ bk,
                 const __half* __restrict__ Wvh, const float* __restrict__ bv,
                 const __half* __restrict__ XS, __half* __restrict__ Yk,
                 __half* __restrict__ Yv)
{
    const int tid = threadIdx.x;
    const int wv = tid >> 6;
    const int lane = tid & 63;
    const int l15 = lane & 15, lhi = lane >> 4;
    const int otile = blockIdx.y * 64 + wv * 16;
    const int stile = blockIdx.x * 32;
    const int b = blockIdx.z;

    const __half* Wkp = Wkh + (size_t)(otile + l15) * CIN + lhi * 8;
    const __half* Wvp = Wvh + (size_t)(otile + l15) * CIN + lhi * 8;
    const __half* Xp0 = XS + ((size_t)(b * NS_ + stile + l15)) * CIN + lhi * 8;
    const __half* Xp1 = Xp0 + (size_t)16 * CIN;

    f32x4_t ka0 = {0.f,0.f,0.f,0.f}, ka1 = {0.f,0.f,0.f,0.f};
    f32x4_t va0 = {0.f,0.f,0.f,0.f}, va1 = {0.f,0.f,0.f,0.f};
#pragma unroll
    for (int c0 = 0; c0 < CIN; c0 += 32) {
        half8_t ak = *(const half8_t*)(Wkp + c0);
        half8_t av = *(const half8_t*)(Wvp + c0);
        half8_t b0 = *(const half8_t*)(Xp0 + c0);
        half8_t b1 = *(const half8_t*)(Xp1 + c0);
        ka0 = __builtin_amdgcn_mfma_f32_16x16x32_f16(ak, b0, ka0, 0, 0, 0);
        ka1 = __builtin_amdgcn_mfma_f32_16x16x32_f16(ak, b1, ka1, 0, 0, 0);
        va0 = __builtin_amdgcn_mfma_f32_16x16x32_f16(av, b0, va0, 0, 0, 0);
        va1 = __builtin_amdgcn_mfma_f32_16x16x32_f16(av, b1, va1, 0, 0, 0);
    }
    const int h = otile >> 5;
    const int c32 = (otile & 31) + lhi * 4;
    const size_t bh = (size_t)(b * NHD + h);
    float bkv[4], bvv[4];
#pragma unroll
    for (int r = 0; r < 4; ++r) {
        bkv[r] = bk[otile + lhi * 4 + r];
        bvv[r] = bv[otile + lhi * 4 + r];
    }
    {
        size_t base = (bh * NS_ + stile + l15) * 32 + c32;
        __half2 kh[2];
        kh[0] = __floats2half2_rn(ka0[0] + bkv[0], ka0[1] + bkv[1]);
        kh[1] = __floats2half2_rn(ka0[2] + bkv[2], ka0[3] + bkv[3]);
        *(uint2*)(Yk + base) = *(uint2*)kh;
        base = (bh * NS_ + stile + 16 + l15) * 32 + c32;
        kh[0] = __floats2half2_rn(ka1[0] + bkv[0], ka1[1] + bkv[1]);
        kh[1] = __floats2half2_rn(ka1[2] + bkv[2], ka1[3] + bkv[3]);
        *(uint2*)(Yk + base) = *(uint2*)kh;
    }
    {
        __half* vdst = Yv + (bh * 32 + c32) * NS_;
#pragma unroll
        for (int r = 0; r < 4; ++r) {
            vdst[(size_t)r * NS_ + stile + l15]      = __float2half(va0[r] + bvv[r]);
            vdst[(size_t)r * NS_ + stile + 16 + l15] = __float2half(va1[r] + bvv[r]);
        }
    }
}

// ---------------- K2a: depthwise conv 5x5 stride 2, transposed output [bg][pos][ch] ----------------
__global__ void offset_dw_kernel(const float* __restrict__ qb, const float* __restrict__ dww,
                                 const float* __restrict__ dwb, float* __restrict__ cobuf)
{
    __shared__ float img[HWSZ];
    const int c = blockIdx.x, bg = blockIdx.y;
    const int b = bg / GG, g = bg - b * GG;
    const int tid = threadIdx.x;
    const float* src = qb + ((size_t)(b * CC_ + g * NGC_ + c)) * HWSZ;
    ((float4*)img)[tid] = ((const float4*)src)[tid];
    __syncthreads();
    const int oy = tid >> 4, ox = tid & 15;
    float s = dwb[c];
    const float* wf = dww + c * 25;
    const int iy0 = oy * 2 - 2, ix0 = ox * 2 - 2;
#pragma unroll
    for (int ky = 0; ky < 5; ++ky) {
        int iy = iy0 + ky;
        if (iy < 0 || iy > 31) continue;
#pragma unroll
        for (int kx = 0; kx < 5; ++kx) {
            int ix = ix0 + kx;
            if (ix < 0 || ix > 31) continue;
            s = fmaf(img[iy * 32 + ix], wf[ky * 5 + kx], s);
        }
    }
    cobuf[((size_t)(bg * 256 + tid)) * NGC_ + c] = s;
}

// ---------------- K2b+K3 fused: LN+GELU+pw+tanh -> pos, bilinear sample of xh -> xsh ----------------
// grid: 1536 blocks x 256 thr = 4 waves; wave = 1 position (lane = channel).
// Phase 2 reads xh fp16 [b][n][c]: lane=channel contiguous -> coalesced 128B taps.
__global__ void offset_finsample_kernel(const float* __restrict__ cobuf, const float* __restrict__ lng,
                                        const float* __restrict__ lnb, const float* __restrict__ pww,
                                        const __half* __restrict__ xh, float* __restrict__ posb,
                                        __half* __restrict__ xsh)
{
    __shared__ float pos_s[8];
    const int lane = threadIdx.x & 63;
    const int wv = threadIdx.x >> 6;
    const int gpos = blockIdx.x * 4 + wv;
    const int bg = gpos >> 8, pos = gpos & 255;
    const int oy = (pos >> 4), ox = pos & 15;
    const int b = bg / GG, g = bg - b * GG;

    float v = cobuf[(size_t)gpos * NGC_ + lane];
    float s1 = v, s2 = v * v;
#pragma unroll
    for (int off = 32; off >= 1; off >>= 1) {
        s1 += __shfl_xor(s1, off);
        s2 += __shfl_xor(s2, off);
    }
    float mu = s1 * (1.f / 64.f);
    float var = s2 * (1.f / 64.f) - mu * mu;
    float rstd = rsqrtf(var + 1e-5f);
    float t = (v - mu) * rstd * lng[lane] + lnb[lane];
    float gv = 0.5f * t * (1.f + erff(t * 0.70710678118654752f));
    float o0 = pww[lane] * gv;
    float o1 = pww[64 + lane] * gv;
#pragma unroll
    for (int off = 32; off >= 1; off >>= 1) {
        o0 += __shfl_xor(o0, off);
        o1 += __shfl_xor(o1, off);
    }
    if (lane == 0) {
        float py = tanhf(o0) * (2.f / 15.f) + ((0.5f + (float)oy) * (1.f / 15.f)) * 2.f - 1.f;
        float px = tanhf(o1) * (2.f / 15.f) + ((0.5f + (float)ox) * (1.f / 15.f)) * 2.f - 1.f;
        posb[bg * 512 + pos * 2 + 0] = py;
        posb[bg * 512 + pos * 2 + 1] = px;
        pos_s[wv * 2 + 0] = py;
        pos_s[wv * 2 + 1] = px;
    }
    __syncthreads();

    float py = pos_s[wv * 2 + 0], px = pos_s[wv * 2 + 1];
    float xi = (px + 1.f) * 0.5f * 31.f;
    float yi = (py + 1.f) * 0.5f * 31.f;
    float x0f = floorf(xi), y0f = floorf(yi);
    int x0 = (int)x0f, y0 = (int)y0f;
    float wx1 = xi - x0f, wy1 = yi - y0f;
    const __half* imgc = xh + (size_t)(b * HWSZ) * CC_ + g * NGC_ + lane;
    float acc = 0.f;
#pragma unroll
    for (int tt = 0; tt < 4; ++tt) {
        int iy = y0 + (tt >> 1), ix = x0 + (tt & 1);
        float w = ((tt >> 1) ? wy1 : 1.f - wy1) * ((tt & 1) ? wx1 : 1.f - wx1);
        if (iy >= 0 && iy <= 31 && ix >= 0 && ix <= 31)
            acc = fmaf(__half2float(imgc[(size_t)(iy * 32 + ix) * CC_]), w, acc);
    }
    xsh[((size_t)(b * NS_ + pos)) * CC_ + g * NGC_ + lane] = __float2half(acc);
}

// ---------------- K5: full-MFMA attention, 8 waves / 128 q per block ----------------
// grid (8 qtiles128, 48 bh), block 512. Block covers rows {4*bx .. 4*bx+3}.
__launch_bounds__(512)
__global__ void attn_mfma(const __half* __restrict__ qh, const __half* __restrict__ kt,
                          const __half* __restrict__ vt, const float* __restrict__ posb,
                          const float* __restrict__ rpe, __half* __restrict__ aoT)
{
    __shared__ __half rph[4096];
    __shared__ float4 ytab[1024];
    const int bh = blockIdx.y;
    const int b = bh / NHD, h = bh - b * NHD;
    const int bg = b * GG + (h >> 1);
    const int tid = threadIdx.x;
    for (int e = tid; e < RPEW * RPEW; e += 512)
        rph[e] = __float2half(rpe[(size_t)h * (RPEW * RPEW) + e]);
    const int base_row = blockIdx.x * 4;
    for (int e = tid; e < 1024; e += 512) {
        int rr = e >> 8, s = e & 255;
        float py = posb[bg * 512 + s * 2 + 0];
        float px = posb[bg * 512 + s * 2 + 1];
        float ycr = ((float)(base_row + rr) * (2.f / 31.f) - 1.f) * 15.5f + 31.f;
        float yi = fmaf(py, -15.5f, ycr);
        float y0f = floorf(yi);
        int iy = (int)y0f;
        float wy1 = yi - y0f, wy0 = 1.f - wy1;
        if ((unsigned)iy > 62u)       wy0 = 0.f;
        if ((unsigned)(iy + 1) > 62u) wy1 = 0.f;
        int ry0 = min(max(iy, 0), 62) * 63;
        int ry1 = min(max(iy + 1, 0), 62) * 63;
        float4 t;
        t.x = __int_as_float(ry0);
        t.y = __int_as_float(ry1);
        t.z = __uint_as_float(__builtin_bit_cast(unsigned, __floats2half2_rn(wy0, wy1)));
        t.w = px * 15.5f;
        ytab[rr * 256 + s] = t;
    }
    __syncthreads();

    const int wave = tid >> 6;
    const int lane = tid & 63;
    const int l15 = lane & 15, lhi = lane >> 4;
    const int qglob = blockIdx.x * 128 + wave * 16 + l15;
    const int col = qglob & 31;
    const float xc = ((float)col * (2.f / 31.f) - 1.f) * 15.5f + 31.f;
    const int rowl = wave >> 1;      // row within block (0..3), wave-uniform

    half8_t qf = *(const half8_t*)(qh + ((size_t)(b * HWSZ + qglob)) * CC_ + h * HCH + lhi * 8);

    const __half* kbase = kt + (size_t)bh * NS_ * 32;
    const __half* vbase = vt + (size_t)bh * 32 * NS_;

    f32x4_t oacc0 = {0.f,0.f,0.f,0.f}, oacc1 = {0.f,0.f,0.f,0.f};
    const f32x4_t zero4 = {0.f,0.f,0.f,0.f};
    float lsum = 0.f;

    for (int chunk = 0; chunk < 8; ++chunk) {
        const int sbase = chunk * 32;
        unsigned wa0 = 0, wa1 = 0, wb0 = 0, wb1 = 0;
#pragma unroll
        for (int t = 0; t < 2; ++t) {
            const int stile = sbase + t * 16;
            half8_t kf = *(const half8_t*)(kbase + (size_t)(stile + l15) * 32 + lhi * 8);
            f32x4_t sf = __builtin_amdgcn_mfma_f32_16x16x32_f16(kf, qf, zero4, 0, 0, 0);
            float pv[4];
#pragma unroll
            for (int r = 0; r < 4; ++r) {
                const int s = stile + lhi * 4 + r;
                float4 yt = ytab[rowl * 256 + s];
                int ry0 = __float_as_int(yt.x), ry1 = __float_as_int(yt.y);
                __half2 wyh = __builtin_bit_cast(__half2, __float_as_uint(yt.z));
                float wy0 = __low2float(wyh), wy1 = __high2float(wyh);
                float xi = xc - yt.w;
                float x0f = floorf(xi);
                int ix = (int)x0f;
                float wx1 = xi - x0f, wx0 = 1.f - wx1;
                if ((unsigned)ix > 62u)       wx0 = 0.f;
                if ((unsigned)(ix + 1) > 62u) wx1 = 0.f;
                int cx0 = min(max(ix, 0), 62);
                int cx1 = min(max(ix + 1, 0), 62);
                float t00 = __half2float(rph[ry0 + cx0]), t01 = __half2float(rph[ry0 + cx1]);
                float t10 = __half2float(rph[ry1 + cx0]), t11 = __half2float(rph[ry1 + cx1]);
                float bias = wy0 * fmaf(wx0, t00, wx1 * t01)
                           + wy1 * fmaf(wx0, t10, wx1 * t11);
                float p = __expf(sf[r] + bias);
                lsum += p;
                pv[r] = p;
            }
            unsigned w0 = __builtin_bit_cast(unsigned, __floats2half2_rn(pv[0], pv[1]));
            unsigned w1 = __builtin_bit_cast(unsigned, __floats2half2_rn(pv[2], pv[3]));
            if (t == 0) { wa0 = w0; wa1 = w1; } else { wb0 = w0; wb1 = w1; }
        }
        const int srcA = l15 + ((lhi & 1) << 5);
        const int srcB = srcA + 16;
        int g0a = __shfl((int)wa0, srcA), g0b = __shfl((int)wb0, srcA);
        int g1a = __shfl((int)wa1, srcA), g1b = __shfl((int)wb1, srcA);
        int g2a = __shfl((int)wa0, srcB), g2b = __shfl((int)wb0, srcB);
        int g3a = __shfl((int)wa1, srcB), g3b = __shfl((int)wb1, srcB);
        const bool hi = (lhi >= 2);
        u32x4_t bw;
        bw[0] = (unsigned)(hi ? g0b : g0a);
        bw[1] = (unsigned)(hi ? g1b : g1a);
        bw[2] = (unsigned)(hi ? g2b : g2a);
        bw[3] = (unsigned)(hi ? g3b : g3a);
        half8_t pf = __builtin_bit_cast(half8_t, bw);
        half8_t vf0 = *(const half8_t*)(vbase + (size_t)(l15) * NS_ + sbase + lhi * 8);
        half8_t vf1 = *(const half8_t*)(vbase + (size_t)(16 + l15) * NS_ + sbase + lhi * 8);
        oacc0 = __builtin_amdgcn_mfma_f32_16x16x32_f16(vf0, pf, oacc0, 0, 0, 0);
        oacc1 = __builtin_amdgcn_mfma_f32_16x16x32_f16(vf1, pf, oacc1, 0, 0, 0);
    }
    lsum += __shfl_xor(lsum, 16);
    lsum += __shfl_xor(lsum, 32);
    const float inv = 1.f / lsum;
    __half* og = aoT + ((size_t)(b * HWSZ + qglob)) * CC_ + h * HCH;
    {
        __half2 h0 = __floats2half2_rn(oacc0[0] * inv, oacc0[1] * inv);
        __half2 h1 = __floats2half2_rn(oacc0[2] * inv, oacc0[3] * inv);
        uint2 u;
        u.x = __builtin_bit_cast(unsigned, h0);
        u.y = __builtin_bit_cast(unsigned, h1);
        *(uint2*)(og + lhi * 4) = u;
        h0 = __floats2half2_rn(oacc1[0] * inv, oacc1[1] * inv);
        h1 = __floats2half2_rn(oacc1[2] * inv, oacc1[3] * inv);
        u.x = __builtin_bit_cast(unsigned, h0);
        u.y = __builtin_bit_cast(unsigned, h1);
        *(uint2*)(og + 16 + lhi * 4) = u;
    }
}

extern "C" void kernel_launch(void* const* d_in, const int* in_sizes, int n_in,
                              void* d_out, int out_size, void* d_ws, size_t ws_size,
                              hipStream_t stream) {
    (void)in_sizes; (void)n_in; (void)out_size; (void)ws_size;
    const float* x   = (const float*)d_in[0];
    const float* Wq  = (const float*)d_in[1];
    const float* bq  = (const float*)d_in[2];
    const float* Wk  = (const float*)d_in[3];
    const float* bk  = (const float*)d_in[4];
    const float* Wv  = (const float*)d_in[5];
    const float* bv  = (const float*)d_in[6];
    const float* Wo  = (const float*)d_in[7];
    const float* bo  = (const float*)d_in[8];
    const float* dww = (const float*)d_in[9];
    const float* dwb = (const float*)d_in[10];
    const float* lng = (const float*)d_in[11];
    const float* lnb = (const float*)d_in[12];
    const float* pww = (const float*)d_in[13];
    const float* rpe = (const float*)d_in[14];
    float* out = (float*)d_out;

    // Workspace (float slots). Aliasing audited:
    //  cobuf (393216) aliases ktb+vth (196608+196608): dw writes cobuf ->
    //    finsample reads cobuf -> convkv overwrites as ktb/vth. Ordering-safe.
    //  xh stays live prep..finsample (own region now).
    //  qh == aoT alias (attn reads/writes same per-block region).
    float* p = (float*)d_ws;
    float* qbuf  = p; p += 1572864;                 // fp32 [b][c][n]
    float* posb  = p; p += 12288;
    __half* ktb  = (__half*)p; p += 196608;         // K fp16 [bh][s][32]
    __half* vth  = (__half*)p; p += 196608;         // V fp16 [bh][c][s]
    float* cobuf = (float*)ktb;                     // alias (see above)
    __half* xh   = (__half*)p; p += 786432;         // fp16 [b][n][c]
    __half* qh   = (__half*)p; p += 786432;         // fp16 scaled [b][n][c]
    __half* aoT  = qh;
    __half* wqh  = (__half*)p; p += 73728;
    __half* woh  = (__half*)p; p += 73728;
    __half* wkh  = (__half*)p; p += 73728;
    __half* wvh  = (__half*)p; p += 73728;
    __half* xsh  = (__half*)p; p += 196608;         // fp16 [b][s][c]
    // total 4,042,752 floats = 16.17 MB (same as validated R16-R19)

    prep_kernel<<<dim3(960), 256, 0, stream>>>(Wq, Wo, Wk, Wv, wqh, woh, wkh, wvh, x, xh);
    convq_mfma<<<dim3(HWSZ / 32, CC_ / 64, BB), 256, 0, stream>>>(wqh, bq, xh, qbuf, qh);
    offset_dw_kernel<<<dim3(NGC_, 24), 256, 0, stream>>>(qbuf, dww, dwb, cobuf);
    offset_finsample_kernel<<<dim3(1536), 256, 0, stream>>>(cobuf, lng, lnb, pww, xh, posb, xsh);
    convkv_mfma<CC_><<<dim3(NS_ / 32, CC_ / 64, BB), 256, 0, stream>>>(wkh, bk, wvh, bv, xsh, ktb, vth);
    attn_mfma<<<dim3(8, BB * NHD), 512, 0, stream>>>(qh, ktb, vth, posb, rpe, aoT);
    conv1x1_mfma_h<CC_><<<dim3(HWSZ / 32, CC_ / 64, BB), 256, 0, stream>>>(woh, bo, aoT, out, HWSZ, CC_);
}